// Round 6
// baseline (1916.042 us; speedup 1.0000x reference)
//
#include <hip/hip_runtime.h>
#include <math.h>

constexpr int N_NODES = 40000;
constexpr int N_EDGES = 500000;
constexpr int ETOT    = N_EDGES + N_NODES;
constexpr int IN_DIM  = 128;
constexpr int ED_DIM  = 16;
constexpr int FEAT    = 256;   // H*C for every layer
constexpr int BATCH   = 128;
constexpr float NEG   = 0.2f;
constexpr int NCHUNK  = (N_NODES + 255) / 256;  // 157
constexpr int LCH     = 128;   // CSR positions per k_logit block

// ---------------- CSR build (by dst, incl. self loops) ----------------
__global__ __launch_bounds__(256) void k_deg(const int* __restrict__ dst, int* __restrict__ deg)
{
    int e = blockIdx.x * 256 + threadIdx.x;
    if (e >= ETOT) return;
    int v = e < N_EDGES ? dst[e] : e - N_EDGES;
    atomicAdd(&deg[v], 1);
}

__global__ __launch_bounds__(256) void k_scan1(const int* __restrict__ deg, int* __restrict__ bsum)
{
    __shared__ int s[256];
    int t = threadIdx.x;
    int idx = blockIdx.x * 256 + t;
    s[t] = idx < N_NODES ? deg[idx] : 0;
    __syncthreads();
    for (int st = 128; st; st >>= 1) { if (t < st) s[t] += s[t + st]; __syncthreads(); }
    if (t == 0) bsum[blockIdx.x] = s[0];
}

__global__ __launch_bounds__(256) void k_scan2(const int* __restrict__ bsum,
    int* __restrict__ boff, int* __restrict__ rowptr)
{
    __shared__ int s[256];
    int t = threadIdx.x;
    int v = t < NCHUNK ? bsum[t] : 0;
    s[t] = v;
    __syncthreads();
    for (int off = 1; off < 256; off <<= 1) {
        int x = (t >= off) ? s[t - off] : 0;
        __syncthreads();
        s[t] += x;
        __syncthreads();
    }
    if (t < NCHUNK) boff[t] = s[t] - v;
    if (t == 0) rowptr[N_NODES] = ETOT;
}

__global__ __launch_bounds__(256) void k_scan3(const int* __restrict__ deg,
    const int* __restrict__ boff, int* __restrict__ rowptr)
{
    __shared__ int s[256];
    int t = threadIdx.x;
    int idx = blockIdx.x * 256 + t;
    int v = idx < N_NODES ? deg[idx] : 0;
    s[t] = v;
    __syncthreads();
    for (int off = 1; off < 256; off <<= 1) {
        int x = (t >= off) ? s[t - off] : 0;
        __syncthreads();
        s[t] += x;
        __syncthreads();
    }
    if (idx < N_NODES) rowptr[idx] = boff[blockIdx.x] + s[t] - v;
}

// elist4[pos] = (src, eid, dst, 0)
__global__ __launch_bounds__(256) void k_fill(const int* __restrict__ srcA, const int* __restrict__ dst,
    const int* __restrict__ rowptr, int* __restrict__ fill, int4* __restrict__ elist4)
{
    int e = blockIdx.x * 256 + threadIdx.x;
    if (e >= ETOT) return;
    int v = e < N_EDGES ? dst[e]  : e - N_EDGES;
    int s = e < N_EDGES ? srcA[e] : e - N_EDGES;
    int pos = rowptr[v] + atomicAdd(&fill[v], 1);
    elist4[pos] = make_int4(s, e, v, 0);
}

// ---------------- self-loop mean edge attr via CSR (no atomics) ----------------
__global__ __launch_bounds__(256) void k_loop_csr(const int4* __restrict__ elist4,
    const int* __restrict__ rowptr, const float* __restrict__ ea, float* __restrict__ loop_attr)
{
    int t = blockIdx.x * 256 + threadIdx.x;
    if (t >= N_NODES * ED_DIM) return;
    int n = t >> 4, d = t & 15;
    int p0 = rowptr[n], p1 = rowptr[n + 1];
    float s = 0.f; int c = 0;
    for (int p = p0; p < p1; ++p) {
        int e = elist4[p].y;
        if (e < N_EDGES) { s += ea[(size_t)e * ED_DIM + d]; ++c; }
    }
    loop_attr[t] = s / (float)(c > 0 ? c : 1);
}

// ---------------- fp32 GEMM: C[M,N] = A[M,K] @ W[K,N] + bias (+relu) ----------------
__global__ __launch_bounds__(256) void k_gemm(const float* __restrict__ A, const float* __restrict__ W,
    const float* __restrict__ bias, float* __restrict__ C, int M, int N, int K, int act)
{
    __shared__ float As[16][136];   // [k][m]
    __shared__ float Bs[16][136];   // [k][n]
    int t = threadIdx.x;
    int bm = blockIdx.x * 128, bn = blockIdx.y * 128;
    int tr = t >> 4, tc = t & 15;
    int mr0 = tr * 8, nc0 = tc * 4;

    int ar0 = t >> 1,        ak0 = (t & 1) << 3;
    int bk0 = t >> 5,        bn0 = (t & 31) << 2;

    float acc[8][8] = {};

    int r0 = bm + ar0; r0 = r0 < M ? r0 : M - 1;
    float4 avA = *(const float4*)(A + (size_t)r0 * K + ak0);
    float4 avB = *(const float4*)(A + (size_t)r0 * K + ak0 + 4);
    float4 bvA = *(const float4*)(W + (size_t)bk0 * N + bn + bn0);
    float4 bvB = *(const float4*)(W + (size_t)(bk0 + 8) * N + bn + bn0);

    for (int k0 = 0; k0 < K; k0 += 16) {
        __syncthreads();
        As[ak0 + 0][ar0] = avA.x; As[ak0 + 1][ar0] = avA.y;
        As[ak0 + 2][ar0] = avA.z; As[ak0 + 3][ar0] = avA.w;
        As[ak0 + 4][ar0] = avB.x; As[ak0 + 5][ar0] = avB.y;
        As[ak0 + 6][ar0] = avB.z; As[ak0 + 7][ar0] = avB.w;
        *(float4*)&Bs[bk0][bn0]     = bvA;
        *(float4*)&Bs[bk0 + 8][bn0] = bvB;
        __syncthreads();
        if (k0 + 16 < K) {
            avA = *(const float4*)(A + (size_t)r0 * K + k0 + 16 + ak0);
            avB = *(const float4*)(A + (size_t)r0 * K + k0 + 16 + ak0 + 4);
            bvA = *(const float4*)(W + (size_t)(k0 + 16 + bk0) * N + bn + bn0);
            bvB = *(const float4*)(W + (size_t)(k0 + 24 + bk0) * N + bn + bn0);
        }
        #pragma unroll
        for (int k = 0; k < 16; ++k) {
            float4 a0 = *(const float4*)&As[k][mr0];
            float4 a1 = *(const float4*)&As[k][mr0 + 4];
            float4 b0 = *(const float4*)&Bs[k][nc0];
            float4 b1 = *(const float4*)&Bs[k][64 + nc0];
            float am[8] = {a0.x, a0.y, a0.z, a0.w, a1.x, a1.y, a1.z, a1.w};
            float bv[8] = {b0.x, b0.y, b0.z, b0.w, b1.x, b1.y, b1.z, b1.w};
            #pragma unroll
            for (int i = 0; i < 8; ++i)
                #pragma unroll
                for (int j = 0; j < 8; ++j)
                    acc[i][j] = fmaf(am[i], bv[j], acc[i][j]);
        }
    }

    float bb[8];
    #pragma unroll
    for (int j = 0; j < 4; ++j) { bb[j] = bias[bn + nc0 + j]; bb[j + 4] = bias[bn + 64 + nc0 + j]; }
    #pragma unroll
    for (int i = 0; i < 8; ++i) {
        int row = bm + mr0 + i;
        if (row >= M) break;
        float4 o0, o1;
        o0.x = acc[i][0] + bb[0]; o0.y = acc[i][1] + bb[1];
        o0.z = acc[i][2] + bb[2]; o0.w = acc[i][3] + bb[3];
        o1.x = acc[i][4] + bb[4]; o1.y = acc[i][5] + bb[5];
        o1.z = acc[i][6] + bb[6]; o1.w = acc[i][7] + bb[7];
        if (act) {
            o0.x = fmaxf(o0.x, 0.f); o0.y = fmaxf(o0.y, 0.f); o0.z = fmaxf(o0.z, 0.f); o0.w = fmaxf(o0.w, 0.f);
            o1.x = fmaxf(o1.x, 0.f); o1.y = fmaxf(o1.y, 0.f); o1.z = fmaxf(o1.z, 0.f); o1.w = fmaxf(o1.w, 0.f);
        }
        *(float4*)(C + (size_t)row * N + bn + nc0)      = o0;
        *(float4*)(C + (size_t)row * N + bn + 64 + nc0) = o1;
    }
}

static void launch_gemm(const float* A, const float* W, const float* bias, float* C,
                        int M, int N, int K, int act, hipStream_t stream)
{
    dim3 grid((M + 127) / 128, N / 128);
    k_gemm<<<grid, 256, 0, stream>>>(A, W, bias, C, M, N, K, act);
}

// ---------------- pass A: per-edge logits, thread == channel ----------------
// Block walks LCH consecutive CSR positions. Thread t owns channel t; We fragment
// is 16 VGPRs. Wave w reduces its 64 channels; writes lg4[pos].w:
//   H=4: per-head logit (head == wave), H=1: partial sum (pass B adds the 4).
__global__ __launch_bounds__(256) void k_logit(
    const float* __restrict__ xl, const float* __restrict__ xr,
    const float* __restrict__ ea, const float* __restrict__ loop_attr,
    const int4* __restrict__ elist4, const float* __restrict__ We,
    const float* __restrict__ att, float* __restrict__ lg)
{
    int t = threadIdx.x;
    int w = t >> 6;

    float weF[ED_DIM];
    #pragma unroll
    for (int d = 0; d < ED_DIM; ++d) weF[d] = We[d * FEAT + t];
    float attT = att[t];

    int p0 = blockIdx.x * LCH;
    int p1 = p0 + LCH; p1 = p1 < ETOT ? p1 : ETOT;

    for (int pos = p0; pos < p1; ++pos) {
        int4 e4 = elist4[pos];                       // uniform -> scalar load
        const float* eaP = (e4.y < N_EDGES) ? ea + (size_t)e4.y * ED_DIM
                                            : loop_attr + (size_t)e4.x * ED_DIM;
        float4 q0 = ((const float4*)eaP)[0];
        float4 q1 = ((const float4*)eaP)[1];
        float4 q2 = ((const float4*)eaP)[2];
        float4 q3 = ((const float4*)eaP)[3];
        float ev[ED_DIM] = {q0.x,q0.y,q0.z,q0.w, q1.x,q1.y,q1.z,q1.w,
                            q2.x,q2.y,q2.z,q2.w, q3.x,q3.y,q3.z,q3.w};

        float u = xl[(size_t)e4.x * FEAT + t] + xr[(size_t)e4.z * FEAT + t];
        #pragma unroll
        for (int d = 0; d < ED_DIM; ++d) u = fmaf(ev[d], weF[d], u);
        u = fmaxf(u, 0.f) + NEG * fminf(u, 0.f);
        float v = u * attT;

        v += __shfl_xor(v, 1, 64);
        v += __shfl_xor(v, 2, 64);
        v += __shfl_xor(v, 4, 64);
        v += __shfl_xor(v, 8, 64);
        v += __shfl_xor(v, 16, 64);
        v += __shfl_xor(v, 32, 64);

        if ((t & 63) == 0) lg[pos * 4 + w] = v;
    }
}

// ---------------- pass B: per-dst online softmax + aggregate ----------------
// channel idx(j) = q*64 + u + 16*j, q = lane>>4 (== head for H=4), u = lane&15.
#define AGG_LOAD(s, pp) do {                                                          \
    int pos_ = (pp);                                                                  \
    srcS[s] = elist4[pos_].x;                                                         \
    float4 lv_ = ((const float4*)lg)[pos_];                                           \
    lS[s] = (H == 4) ? (q == 0 ? lv_.x : q == 1 ? lv_.y : q == 2 ? lv_.z : lv_.w)     \
                     : (lv_.x + lv_.y + lv_.z + lv_.w);                               \
    const float* xp_ = xl + (size_t)srcS[s] * FEAT + base;                            \
    xlvS[s][0] = xp_[0];  xlvS[s][1] = xp_[16];                                       \
    xlvS[s][2] = xp_[32]; xlvS[s][3] = xp_[48];                                       \
} while (0)

#define AGG_COMPUTE(s) do {                                                           \
    float l_ = lS[s];                                                                 \
    float nm_ = fmaxf(m, l_);                                                         \
    float sc_ = __expf(m - nm_);                                                      \
    float w_  = __expf(l_ - nm_);                                                     \
    z = fmaf(z, sc_, w_);                                                             \
    m = nm_;                                                                          \
    acc[0] = fmaf(acc[0], sc_, w_ * xlvS[s][0]);                                      \
    acc[1] = fmaf(acc[1], sc_, w_ * xlvS[s][1]);                                      \
    acc[2] = fmaf(acc[2], sc_, w_ * xlvS[s][2]);                                      \
    acc[3] = fmaf(acc[3], sc_, w_ * xlvS[s][3]);                                      \
} while (0)

template <int H, int RELU>
__global__ __launch_bounds__(256) void k_agg(
    const float* __restrict__ xl, const float* __restrict__ lg,
    const int4* __restrict__ elist4, const int* __restrict__ rowptr,
    const float* __restrict__ bias, float* __restrict__ out)
{
    int t = threadIdx.x;
    int lane = t & 63;
    int n = __builtin_amdgcn_readfirstlane(blockIdx.x * 4 + (t >> 6));
    int q = lane >> 4;
    int u = lane & 15;
    int base = q * 64 + u;

    float m = -INFINITY, z = 0.f;
    float acc[4] = {0.f, 0.f, 0.f, 0.f};

    int p0 = rowptr[n], p1 = rowptr[n + 1];   // p1 > p0 guaranteed (self-loop)
    int pe = p1 - 1;

    int   srcS[2];
    float lS[2];
    float xlvS[2][4];

    AGG_LOAD(0, p0);

    int p = p0;
    while (true) {
        { int pn = p + 1 > pe ? pe : p + 1; AGG_LOAD(1, pn); }
        AGG_COMPUTE(0);
        if (++p >= p1) break;
        { int pn = p + 1 > pe ? pe : p + 1; AGG_LOAD(0, pn); }
        AGG_COMPUTE(1);
        if (++p >= p1) break;
    }

    float inv = 1.0f / (z + 1e-16f);
    #pragma unroll
    for (int j = 0; j < 4; ++j) {
        float o = fmaf(acc[j], inv, bias[base + 16 * j]);
        if (RELU) o = fmaxf(o, 0.f);
        out[(size_t)n * FEAT + base + 16 * j] = o;
    }
}

// ---------------- gate score: gate[n] = ghid[n,:] @ W2 + b2 ----------------
__global__ __launch_bounds__(256) void k_gate_score(const float* __restrict__ ghid,
    const float* __restrict__ W2, const float* __restrict__ b2, float* __restrict__ gate)
{
    int lane = threadIdx.x & 63;
    int n = blockIdx.x * 4 + (threadIdx.x >> 6);
    float v = ghid[(size_t)n * 128 + lane] * W2[lane] + ghid[(size_t)n * 128 + lane + 64] * W2[lane + 64];
    #pragma unroll
    for (int off = 32; off > 0; off >>= 1) v += __shfl_xor(v, off, 64);
    if (lane == 0) gate[n] = v + b2[0];
}

// ---------------- attentional pooling: one block per batch segment ----------------
__device__ __forceinline__ int lbound(const int* a, int n, int v)
{
    int lo = 0, hi = n;
    while (lo < hi) { int mid = (lo + hi) >> 1; if (a[mid] < v) lo = mid + 1; else hi = mid; }
    return lo;
}

__global__ __launch_bounds__(256) void k_pool(const float* __restrict__ gate,
    const float* __restrict__ h, const int* __restrict__ batch, float* __restrict__ g)
{
    int b = blockIdx.x;
    int t = threadIdx.x;
    __shared__ float red[256];
    int start = lbound(batch, N_NODES, b);
    int end   = lbound(batch, N_NODES, b + 1);

    float mx = -INFINITY;
    for (int n = start + t; n < end; n += 256) mx = fmaxf(mx, gate[n]);
    red[t] = mx; __syncthreads();
    for (int s = 128; s; s >>= 1) { if (t < s) red[t] = fmaxf(red[t], red[t + s]); __syncthreads(); }
    float m = red[0];
    __syncthreads();

    float zs = 0.f;
    for (int n = start + t; n < end; n += 256) zs += __expf(gate[n] - m);
    red[t] = zs; __syncthreads();
    for (int s = 128; s; s >>= 1) { if (t < s) red[t] += red[t + s]; __syncthreads(); }
    float z = red[0];

    float gs = 0.f;
    for (int n = start; n < end; ++n) gs += __expf(gate[n] - m) * h[(size_t)n * FEAT + t];
    g[b * FEAT + t] = gs / (z + 1e-16f);
}

// ---------------- regression head: per-batch tiny MLP ----------------
__global__ __launch_bounds__(128) void k_reg(const float* __restrict__ g,
    const float* __restrict__ W1, const float* __restrict__ b1,
    const float* __restrict__ W2, const float* __restrict__ b2, float* __restrict__ out)
{
    int b = blockIdx.x, t = threadIdx.x;
    __shared__ float sg[FEAT];
    sg[t] = g[b * FEAT + t];
    sg[t + 128] = g[b * FEAT + t + 128];
    __syncthreads();
    float hv = b1[t];
    for (int k = 0; k < FEAT; ++k) hv += sg[k] * W1[k * 128 + t];
    hv = fmaxf(hv, 0.f);
    __shared__ float p0s[128], p1s[128];
    p0s[t] = hv * W2[t * 2 + 0];
    p1s[t] = hv * W2[t * 2 + 1];
    __syncthreads();
    for (int s = 64; s; s >>= 1) {
        if (t < s) { p0s[t] += p0s[t + s]; p1s[t] += p1s[t + s]; }
        __syncthreads();
    }
    if (t == 0) { out[b * 2 + 0] = p0s[0] + b2[0]; out[b * 2 + 1] = p1s[0] + b2[1]; }
}

// ---------------- launch ----------------
extern "C" void kernel_launch(void* const* d_in, const int* in_sizes, int n_in,
                              void* d_out, int out_size, void* d_ws, size_t ws_size,
                              hipStream_t stream)
{
    const float* x       = (const float*)d_in[0];
    const int*   ei      = (const int*)d_in[1];   // [2,E]
    const float* ea      = (const float*)d_in[2];
    const int*   batch   = (const int*)d_in[3];
    const float* c1_Wl   = (const float*)d_in[5];
    const float* c1_bl   = (const float*)d_in[6];
    const float* c1_Wr   = (const float*)d_in[7];
    const float* c1_br   = (const float*)d_in[8];
    const float* c1_We   = (const float*)d_in[9];
    const float* c1_att  = (const float*)d_in[10];
    const float* c1_bias = (const float*)d_in[11];
    const float* c2_Wl   = (const float*)d_in[12];
    const float* c2_bl   = (const float*)d_in[13];
    const float* c2_Wr   = (const float*)d_in[14];
    const float* c2_br   = (const float*)d_in[15];
    const float* c2_We   = (const float*)d_in[16];
    const float* c2_att  = (const float*)d_in[17];
    const float* c2_bias = (const float*)d_in[18];
    const float* c3_Wl   = (const float*)d_in[19];
    const float* c3_bl   = (const float*)d_in[20];
    const float* c3_Wr   = (const float*)d_in[21];
    const float* c3_br   = (const float*)d_in[22];
    const float* c3_We   = (const float*)d_in[23];
    const float* c3_att  = (const float*)d_in[24];
    const float* c3_bias = (const float*)d_in[25];
    const float* gate_W1 = (const float*)d_in[26];
    const float* gate_b1 = (const float*)d_in[27];
    const float* gate_W2 = (const float*)d_in[28];
    const float* gate_b2 = (const float*)d_in[29];
    const float* reg_W1  = (const float*)d_in[30];
    const float* reg_b1  = (const float*)d_in[31];
    const float* reg_W2  = (const float*)d_in[32];
    const float* reg_b2  = (const float*)d_in[33];

    const int* srcArr = ei;            // row 0
    const int* dstArr = ei + N_EDGES;  // row 1

    float* ws = (float*)d_ws;
    size_t off = 0;
    auto alloc = [&](size_t nf) { float* p = ws + off; off += (nf + 63) & ~(size_t)63; return p; };
    float* xl        = alloc((size_t)N_NODES * FEAT);
    float* xr        = alloc((size_t)N_NODES * FEAT);
    float* h         = alloc((size_t)N_NODES * FEAT);
    float* loop_attr = alloc((size_t)N_NODES * ED_DIM);
    float* gpool     = alloc((size_t)BATCH * FEAT);
    float* lg        = alloc((size_t)ETOT * 4);   // per-(pos,head) logits / partials
    int* ibase  = (int*)(ws + off);
    int* deg    = ibase;
    int* fill   = ibase + N_NODES;
    int* rowptr = ibase + 2 * N_NODES;            // N+1 ints
    int* bsum   = ibase + 3 * N_NODES + 64;
    int* boff   = bsum + 256;
    int4* elist4 = (int4*)(boff + 256);           // ETOT int4

    // aliases at disjoint lifetimes
    float* ghid = xl;                       // after L3 agg, xl is dead
    float* gate = xr;

    hipMemsetAsync(deg, 0, (size_t)2 * N_NODES * sizeof(int), stream);

    // CSR build, then self-loop mean attrs from CSR
    k_deg<<<(ETOT + 255) / 256, 256, 0, stream>>>(dstArr, deg);
    k_scan1<<<NCHUNK, 256, 0, stream>>>(deg, bsum);
    k_scan2<<<1, 256, 0, stream>>>(bsum, boff, rowptr);
    k_scan3<<<NCHUNK, 256, 0, stream>>>(deg, boff, rowptr);
    k_fill<<<(ETOT + 255) / 256, 256, 0, stream>>>(srcArr, dstArr, rowptr, fill, elist4);
    k_loop_csr<<<(N_NODES * ED_DIM + 255) / 256, 256, 0, stream>>>(elist4, rowptr, ea, loop_attr);

    int lblocks = (ETOT + LCH - 1) / LCH;

    // layer 1 (in: x [N,128])
    launch_gemm(x, c1_Wl, c1_bl, xl, N_NODES, FEAT, IN_DIM, 0, stream);
    launch_gemm(x, c1_Wr, c1_br, xr, N_NODES, FEAT, IN_DIM, 0, stream);
    k_logit<<<lblocks, 256, 0, stream>>>(xl, xr, ea, loop_attr, elist4, c1_We, c1_att, lg);
    k_agg<4, 1><<<N_NODES / 4, 256, 0, stream>>>(xl, lg, elist4, rowptr, c1_bias, h);
    // layer 2
    launch_gemm(h, c2_Wl, c2_bl, xl, N_NODES, FEAT, FEAT, 0, stream);
    launch_gemm(h, c2_Wr, c2_br, xr, N_NODES, FEAT, FEAT, 0, stream);
    k_logit<<<lblocks, 256, 0, stream>>>(xl, xr, ea, loop_attr, elist4, c2_We, c2_att, lg);
    k_agg<4, 1><<<N_NODES / 4, 256, 0, stream>>>(xl, lg, elist4, rowptr, c2_bias, h);
    // layer 3 (heads=1, no relu)
    launch_gemm(h, c3_Wl, c3_bl, xl, N_NODES, FEAT, FEAT, 0, stream);
    launch_gemm(h, c3_Wr, c3_br, xr, N_NODES, FEAT, FEAT, 0, stream);
    k_logit<<<lblocks, 256, 0, stream>>>(xl, xr, ea, loop_attr, elist4, c3_We, c3_att, lg);
    k_agg<1, 0><<<N_NODES / 4, 256, 0, stream>>>(xl, lg, elist4, rowptr, c3_bias, h);

    // pooling + head
    launch_gemm(h, gate_W1, gate_b1, ghid, N_NODES, 128, FEAT, 1, stream);
    k_gate_score<<<N_NODES / 4, 256, 0, stream>>>(ghid, gate_W2, gate_b2, gate);
    k_pool<<<BATCH, 256, 0, stream>>>(gate, h, batch, gpool);
    k_reg<<<BATCH, 128, 0, stream>>>(gpool, reg_W1, reg_b1, reg_W2, reg_b2, (float*)d_out);
}

// Round 7
// 1429.990 us; speedup vs baseline: 1.3399x; 1.3399x over previous
//
#include <hip/hip_runtime.h>
#include <math.h>

constexpr int N_NODES = 40000;
constexpr int N_EDGES = 500000;
constexpr int ETOT    = N_EDGES + N_NODES;
constexpr int IN_DIM  = 128;
constexpr int ED_DIM  = 16;
constexpr int FEAT    = 256;   // H*C for every layer
constexpr int BATCH   = 128;
constexpr float NEG   = 0.2f;
constexpr int NCHUNK  = (N_NODES + 255) / 256;  // 157

// ---------------- CSR build (by dst, incl. self loops) ----------------
__global__ __launch_bounds__(256) void k_deg(const int* __restrict__ dst, int* __restrict__ deg)
{
    int e = blockIdx.x * 256 + threadIdx.x;
    if (e >= ETOT) return;
    int v = e < N_EDGES ? dst[e] : e - N_EDGES;
    atomicAdd(&deg[v], 1);
}

__global__ __launch_bounds__(256) void k_scan1(const int* __restrict__ deg, int* __restrict__ bsum)
{
    __shared__ int s[256];
    int t = threadIdx.x;
    int idx = blockIdx.x * 256 + t;
    s[t] = idx < N_NODES ? deg[idx] : 0;
    __syncthreads();
    for (int st = 128; st; st >>= 1) { if (t < st) s[t] += s[t + st]; __syncthreads(); }
    if (t == 0) bsum[blockIdx.x] = s[0];
}

__global__ __launch_bounds__(256) void k_scan2(const int* __restrict__ bsum,
    int* __restrict__ boff, int* __restrict__ rowptr)
{
    __shared__ int s[256];
    int t = threadIdx.x;
    int v = t < NCHUNK ? bsum[t] : 0;
    s[t] = v;
    __syncthreads();
    for (int off = 1; off < 256; off <<= 1) {
        int x = (t >= off) ? s[t - off] : 0;
        __syncthreads();
        s[t] += x;
        __syncthreads();
    }
    if (t < NCHUNK) boff[t] = s[t] - v;
    if (t == 0) rowptr[N_NODES] = ETOT;
}

__global__ __launch_bounds__(256) void k_scan3(const int* __restrict__ deg,
    const int* __restrict__ boff, int* __restrict__ rowptr)
{
    __shared__ int s[256];
    int t = threadIdx.x;
    int idx = blockIdx.x * 256 + t;
    int v = idx < N_NODES ? deg[idx] : 0;
    s[t] = v;
    __syncthreads();
    for (int off = 1; off < 256; off <<= 1) {
        int x = (t >= off) ? s[t - off] : 0;
        __syncthreads();
        s[t] += x;
        __syncthreads();
    }
    if (idx < N_NODES) rowptr[idx] = boff[blockIdx.x] + s[t] - v;
}

// elist2[pos] = (src, eid): kills the dependent srcArr gather in k_gat
__global__ __launch_bounds__(256) void k_fill(const int* __restrict__ srcA, const int* __restrict__ dst,
    const int* __restrict__ rowptr, int* __restrict__ fill, int2* __restrict__ elist2)
{
    int e = blockIdx.x * 256 + threadIdx.x;
    if (e >= ETOT) return;
    int v = e < N_EDGES ? dst[e]  : e - N_EDGES;
    int s = e < N_EDGES ? srcA[e] : e - N_EDGES;
    int pos = rowptr[v] + atomicAdd(&fill[v], 1);
    elist2[pos] = make_int2(s, e);
}

// ---------------- self-loop mean edge attr via CSR (no atomics) ----------------
__global__ __launch_bounds__(256) void k_loop_csr(const int2* __restrict__ elist2,
    const int* __restrict__ rowptr, const float* __restrict__ ea, float* __restrict__ loop_attr)
{
    int t = blockIdx.x * 256 + threadIdx.x;
    if (t >= N_NODES * ED_DIM) return;
    int n = t >> 4, d = t & 15;
    int p0 = rowptr[n], p1 = rowptr[n + 1];
    float s = 0.f; int c = 0;
    for (int p = p0; p < p1; ++p) {
        int e = elist2[p].y;
        if (e < N_EDGES) { s += ea[(size_t)e * ED_DIM + d]; ++c; }
    }
    loop_attr[t] = s / (float)(c > 0 ? c : 1);
}

// ---------------- fp32 GEMM: C[M,N] = A[M,K] @ W[K,N] + bias (+relu) ----------------
// 128x128 tile, 256 threads, 8x8 acc/thread, DOUBLE-BUFFERED LDS:
// one barrier per K-tile; next tile prefetched into regs before compute.
__global__ __launch_bounds__(256) void k_gemm(const float* __restrict__ A, const float* __restrict__ W,
    const float* __restrict__ bias, float* __restrict__ C, int M, int N, int K, int act)
{
    __shared__ float As[2][16][136];   // [buf][k][m]  8.7 KB each
    __shared__ float Bs[2][16][136];   // [buf][k][n]  -> 34.8 KB total
    int t = threadIdx.x;
    int bm = blockIdx.x * 128, bn = blockIdx.y * 128;
    int tr = t >> 4, tc = t & 15;
    int mr0 = tr * 8, nc0 = tc * 4;

    int ar0 = t >> 1, ak0 = (t & 1) << 3;   // A: 128 rows x 2 thr x 8 floats
    int bk0 = t >> 5, bn0 = (t & 31) << 2;  // B: rows bk0, bk0+8 x 4 floats

    float acc[8][8] = {};

    int r0 = bm + ar0; r0 = r0 < M ? r0 : M - 1;
    const float* Arow = A + (size_t)r0 * K;

    // load + stage tile 0
    float4 avA = *(const float4*)(Arow + ak0);
    float4 avB = *(const float4*)(Arow + ak0 + 4);
    float4 bvA = *(const float4*)(W + (size_t)bk0 * N + bn + bn0);
    float4 bvB = *(const float4*)(W + (size_t)(bk0 + 8) * N + bn + bn0);
    As[0][ak0 + 0][ar0] = avA.x; As[0][ak0 + 1][ar0] = avA.y;
    As[0][ak0 + 2][ar0] = avA.z; As[0][ak0 + 3][ar0] = avA.w;
    As[0][ak0 + 4][ar0] = avB.x; As[0][ak0 + 5][ar0] = avB.y;
    As[0][ak0 + 6][ar0] = avB.z; As[0][ak0 + 7][ar0] = avB.w;
    *(float4*)&Bs[0][bk0][bn0]     = bvA;
    *(float4*)&Bs[0][bk0 + 8][bn0] = bvB;
    __syncthreads();

    int nt = K >> 4;
    for (int kt = 0; kt < nt; ++kt) {
        int cur = kt & 1;
        if (kt + 1 < nt) {     // prefetch next tile into regs (latency hidden by compute)
            int k0 = (kt + 1) << 4;
            avA = *(const float4*)(Arow + k0 + ak0);
            avB = *(const float4*)(Arow + k0 + ak0 + 4);
            bvA = *(const float4*)(W + (size_t)(k0 + bk0) * N + bn + bn0);
            bvB = *(const float4*)(W + (size_t)(k0 + bk0 + 8) * N + bn + bn0);
        }
        #pragma unroll
        for (int k = 0; k < 16; ++k) {
            float4 a0 = *(const float4*)&As[cur][k][mr0];
            float4 a1 = *(const float4*)&As[cur][k][mr0 + 4];
            float4 b0 = *(const float4*)&Bs[cur][k][nc0];
            float4 b1 = *(const float4*)&Bs[cur][k][64 + nc0];
            float am[8] = {a0.x, a0.y, a0.z, a0.w, a1.x, a1.y, a1.z, a1.w};
            float bv[8] = {b0.x, b0.y, b0.z, b0.w, b1.x, b1.y, b1.z, b1.w};
            #pragma unroll
            for (int i = 0; i < 8; ++i)
                #pragma unroll
                for (int j = 0; j < 8; ++j)
                    acc[i][j] = fmaf(am[i], bv[j], acc[i][j]);
        }
        if (kt + 1 < nt) {     // write into the other buffer (not read this iter)
            int nxt = cur ^ 1;
            As[nxt][ak0 + 0][ar0] = avA.x; As[nxt][ak0 + 1][ar0] = avA.y;
            As[nxt][ak0 + 2][ar0] = avA.z; As[nxt][ak0 + 3][ar0] = avA.w;
            As[nxt][ak0 + 4][ar0] = avB.x; As[nxt][ak0 + 5][ar0] = avB.y;
            As[nxt][ak0 + 6][ar0] = avB.z; As[nxt][ak0 + 7][ar0] = avB.w;
            *(float4*)&Bs[nxt][bk0][bn0]     = bvA;
            *(float4*)&Bs[nxt][bk0 + 8][bn0] = bvB;
            __syncthreads();
        }
    }

    float bb[8];
    #pragma unroll
    for (int j = 0; j < 4; ++j) { bb[j] = bias[bn + nc0 + j]; bb[j + 4] = bias[bn + 64 + nc0 + j]; }
    #pragma unroll
    for (int i = 0; i < 8; ++i) {
        int row = bm + mr0 + i;
        if (row >= M) break;
        float4 o0, o1;
        o0.x = acc[i][0] + bb[0]; o0.y = acc[i][1] + bb[1];
        o0.z = acc[i][2] + bb[2]; o0.w = acc[i][3] + bb[3];
        o1.x = acc[i][4] + bb[4]; o1.y = acc[i][5] + bb[5];
        o1.z = acc[i][6] + bb[6]; o1.w = acc[i][7] + bb[7];
        if (act) {
            o0.x = fmaxf(o0.x, 0.f); o0.y = fmaxf(o0.y, 0.f); o0.z = fmaxf(o0.z, 0.f); o0.w = fmaxf(o0.w, 0.f);
            o1.x = fmaxf(o1.x, 0.f); o1.y = fmaxf(o1.y, 0.f); o1.z = fmaxf(o1.z, 0.f); o1.w = fmaxf(o1.w, 0.f);
        }
        *(float4*)(C + (size_t)row * N + bn + nc0)      = o0;
        *(float4*)(C + (size_t)row * N + bn + 64 + nc0) = o1;
    }
}

static void launch_gemm(const float* A, const float* W, const float* bias, float* C,
                        int M, int N, int K, int act, hipStream_t stream)
{
    dim3 grid((M + 127) / 128, N / 128);
    k_gemm<<<grid, 256, 0, stream>>>(A, W, bias, C, M, N, K, act);
}

// ---------------- fused GATv2 (R4 version, benched 178 us/layer) ----------------
// channel idx(j) = q*64 + u + 16*j, q = lane>>4 (== head for H=4), u = lane&15.

#define XELOAD(s) do {                                                                \
    int src_ = eS[s].x, e_ = eS[s].y;                                                 \
    const float4* eb4_ = reinterpret_cast<const float4*>(                             \
        (e_ < N_EDGES) ? ea + (size_t)e_ * ED_DIM                                     \
                       : loop_attr + (size_t)src_ * ED_DIM);                          \
    evS[s][0] = eb4_[0]; evS[s][1] = eb4_[1];                                         \
    evS[s][2] = eb4_[2]; evS[s][3] = eb4_[3];                                         \
    const float* xp_ = xl + (size_t)src_ * FEAT + base;                               \
    xlvS[s][0] = xp_[0];  xlvS[s][1] = xp_[16];                                       \
    xlvS[s][2] = xp_[32]; xlvS[s][3] = xp_[48];                                       \
} while (0)

#define COMPUTE(s) do {                                                               \
    float ef0_ = 0.f, ef1_ = 0.f, ef2_ = 0.f, ef3_ = 0.f;                             \
    const float* ed_ = (const float*)evS[s];                                          \
    _Pragma("unroll")                                                                 \
    for (int d_ = 0; d_ < ED_DIM; ++d_) {                                             \
        float a_ = ed_[d_];                                                           \
        ef0_ = fmaf(a_, weR[d_][0], ef0_); ef1_ = fmaf(a_, weR[d_][1], ef1_);         \
        ef2_ = fmaf(a_, weR[d_][2], ef2_); ef3_ = fmaf(a_, weR[d_][3], ef3_);         \
    }                                                                                 \
    float s0_ = xlvS[s][0] + xrv[0] + ef0_;                                           \
    float s1_ = xlvS[s][1] + xrv[1] + ef1_;                                           \
    float s2_ = xlvS[s][2] + xrv[2] + ef2_;                                           \
    float s3_ = xlvS[s][3] + xrv[3] + ef3_;                                           \
    s0_ = fmaxf(s0_, 0.f) + NEG * fminf(s0_, 0.f);                                    \
    s1_ = fmaxf(s1_, 0.f) + NEG * fminf(s1_, 0.f);                                    \
    s2_ = fmaxf(s2_, 0.f) + NEG * fminf(s2_, 0.f);                                    \
    s3_ = fmaxf(s3_, 0.f) + NEG * fminf(s3_, 0.f);                                    \
    float l_ = fmaf(s0_, attR[0], fmaf(s1_, attR[1], fmaf(s2_, attR[2], s3_ * attR[3])));\
    l_ += __shfl_xor(l_, 1, 64);                                                      \
    l_ += __shfl_xor(l_, 2, 64);                                                      \
    l_ += __shfl_xor(l_, 4, 64);                                                      \
    l_ += __shfl_xor(l_, 8, 64);                                                      \
    if (H == 1) { l_ += __shfl_xor(l_, 16, 64); l_ += __shfl_xor(l_, 32, 64); }       \
    float nm_ = fmaxf(m, l_);                                                         \
    float sc_ = __expf(m - nm_);                                                      \
    float w_  = __expf(l_ - nm_);                                                     \
    z = fmaf(z, sc_, w_);                                                             \
    m = nm_;                                                                          \
    acc[0] = fmaf(acc[0], sc_, w_ * xlvS[s][0]);                                      \
    acc[1] = fmaf(acc[1], sc_, w_ * xlvS[s][1]);                                      \
    acc[2] = fmaf(acc[2], sc_, w_ * xlvS[s][2]);                                      \
    acc[3] = fmaf(acc[3], sc_, w_ * xlvS[s][3]);                                      \
} while (0)

template <int H, int RELU>
__global__ __launch_bounds__(256, 3) void k_gat(
    const float* __restrict__ xl, const float* __restrict__ xr,
    const float* __restrict__ ea, const float* __restrict__ loop_attr,
    const int2* __restrict__ elist2, const int* __restrict__ rowptr,
    const float* __restrict__ We, const float* __restrict__ att,
    const float* __restrict__ bias, float* __restrict__ out)
{
    int t = threadIdx.x;
    int lane = t & 63;
    int n = __builtin_amdgcn_readfirstlane(blockIdx.x * 4 + (t >> 6));
    int q = lane >> 4;
    int u = lane & 15;
    int base = q * 64 + u;

    float weR[ED_DIM][4];
    #pragma unroll
    for (int d = 0; d < ED_DIM; ++d) {
        #pragma unroll
        for (int j = 0; j < 4; ++j) weR[d][j] = We[d * FEAT + base + 16 * j];
    }
    #pragma unroll
    for (int d = 0; d < ED_DIM; ++d) {
        #pragma unroll
        for (int j = 0; j < 4; ++j) asm volatile("" : "+v"(weR[d][j]));
    }

    float attR[4], xrv[4];
    #pragma unroll
    for (int j = 0; j < 4; ++j) {
        attR[j] = att[base + 16 * j];
        xrv[j]  = xr[(size_t)n * FEAT + base + 16 * j];
    }

    float m = -INFINITY, z = 0.f;
    float acc[4] = {0.f, 0.f, 0.f, 0.f};

    int p0 = rowptr[n], p1 = rowptr[n + 1];   // p1 > p0 guaranteed (self-loop)
    int pe = p1 - 1;

    int2   eS[2];
    float4 evS[2][4];
    float  xlvS[2][4];

    eS[0] = elist2[p0];
    { int pc = p0 + 1 > pe ? pe : p0 + 1; eS[1] = elist2[pc]; }
    XELOAD(0);

    int p = p0;
    while (true) {
        XELOAD(1);
        { int pn = p + 2 > pe ? pe : p + 2; eS[0] = elist2[pn]; }
        COMPUTE(0);
        if (++p >= p1) break;
        XELOAD(0);
        { int pn = p + 2 > pe ? pe : p + 2; eS[1] = elist2[pn]; }
        COMPUTE(1);
        if (++p >= p1) break;
    }

    float inv = 1.0f / (z + 1e-16f);
    #pragma unroll
    for (int j = 0; j < 4; ++j) {
        float o = fmaf(acc[j], inv, bias[base + 16 * j]);
        if (RELU) o = fmaxf(o, 0.f);
        out[(size_t)n * FEAT + base + 16 * j] = o;
    }
}

// ---------------- gate score: gate[n] = ghid[n,:] @ W2 + b2 ----------------
__global__ __launch_bounds__(256) void k_gate_score(const float* __restrict__ ghid,
    const float* __restrict__ W2, const float* __restrict__ b2, float* __restrict__ gate)
{
    int lane = threadIdx.x & 63;
    int n = blockIdx.x * 4 + (threadIdx.x >> 6);
    float v = ghid[(size_t)n * 128 + lane] * W2[lane] + ghid[(size_t)n * 128 + lane + 64] * W2[lane + 64];
    #pragma unroll
    for (int off = 32; off > 0; off >>= 1) v += __shfl_xor(v, off, 64);
    if (lane == 0) gate[n] = v + b2[0];
}

// ---------------- attentional pooling: one block per batch segment ----------------
__device__ __forceinline__ int lbound(const int* a, int n, int v)
{
    int lo = 0, hi = n;
    while (lo < hi) { int mid = (lo + hi) >> 1; if (a[mid] < v) lo = mid + 1; else hi = mid; }
    return lo;
}

__global__ __launch_bounds__(256) void k_pool(const float* __restrict__ gate,
    const float* __restrict__ h, const int* __restrict__ batch, float* __restrict__ g)
{
    int b = blockIdx.x;
    int t = threadIdx.x;
    __shared__ float red[256];
    int start = lbound(batch, N_NODES, b);
    int end   = lbound(batch, N_NODES, b + 1);

    float mx = -INFINITY;
    for (int n = start + t; n < end; n += 256) mx = fmaxf(mx, gate[n]);
    red[t] = mx; __syncthreads();
    for (int s = 128; s; s >>= 1) { if (t < s) red[t] = fmaxf(red[t], red[t + s]); __syncthreads(); }
    float m = red[0];
    __syncthreads();

    float zs = 0.f;
    for (int n = start + t; n < end; n += 256) zs += __expf(gate[n] - m);
    red[t] = zs; __syncthreads();
    for (int s = 128; s; s >>= 1) { if (t < s) red[t] += red[t + s]; __syncthreads(); }
    float z = red[0];

    float gs = 0.f;
    for (int n = start; n < end; ++n) gs += __expf(gate[n] - m) * h[(size_t)n * FEAT + t];
    g[b * FEAT + t] = gs / (z + 1e-16f);
}

// ---------------- regression head: per-batch tiny MLP ----------------
__global__ __launch_bounds__(128) void k_reg(const float* __restrict__ g,
    const float* __restrict__ W1, const float* __restrict__ b1,
    const float* __restrict__ W2, const float* __restrict__ b2, float* __restrict__ out)
{
    int b = blockIdx.x, t = threadIdx.x;
    __shared__ float sg[FEAT];
    sg[t] = g[b * FEAT + t];
    sg[t + 128] = g[b * FEAT + t + 128];
    __syncthreads();
    float hv = b1[t];
    for (int k = 0; k < FEAT; ++k) hv += sg[k] * W1[k * 128 + t];
    hv = fmaxf(hv, 0.f);
    __shared__ float p0s[128], p1s[128];
    p0s[t] = hv * W2[t * 2 + 0];
    p1s[t] = hv * W2[t * 2 + 1];
    __syncthreads();
    for (int s = 64; s; s >>= 1) {
        if (t < s) { p0s[t] += p0s[t + s]; p1s[t] += p1s[t + s]; }
        __syncthreads();
    }
    if (t == 0) { out[b * 2 + 0] = p0s[0] + b2[0]; out[b * 2 + 1] = p1s[0] + b2[1]; }
}

// ---------------- launch ----------------
extern "C" void kernel_launch(void* const* d_in, const int* in_sizes, int n_in,
                              void* d_out, int out_size, void* d_ws, size_t ws_size,
                              hipStream_t stream)
{
    const float* x       = (const float*)d_in[0];
    const int*   ei      = (const int*)d_in[1];   // [2,E]
    const float* ea      = (const float*)d_in[2];
    const int*   batch   = (const int*)d_in[3];
    const float* c1_Wl   = (const float*)d_in[5];
    const float* c1_bl   = (const float*)d_in[6];
    const float* c1_Wr   = (const float*)d_in[7];
    const float* c1_br   = (const float*)d_in[8];
    const float* c1_We   = (const float*)d_in[9];
    const float* c1_att  = (const float*)d_in[10];
    const float* c1_bias = (const float*)d_in[11];
    const float* c2_Wl   = (const float*)d_in[12];
    const float* c2_bl   = (const float*)d_in[13];
    const float* c2_Wr   = (const float*)d_in[14];
    const float* c2_br   = (const float*)d_in[15];
    const float* c2_We   = (const float*)d_in[16];
    const float* c2_att  = (const float*)d_in[17];
    const float* c2_bias = (const float*)d_in[18];
    const float* c3_Wl   = (const float*)d_in[19];
    const float* c3_bl   = (const float*)d_in[20];
    const float* c3_Wr   = (const float*)d_in[21];
    const float* c3_br   = (const float*)d_in[22];
    const float* c3_We   = (const float*)d_in[23];
    const float* c3_att  = (const float*)d_in[24];
    const float* c3_bias = (const float*)d_in[25];
    const float* gate_W1 = (const float*)d_in[26];
    const float* gate_b1 = (const float*)d_in[27];
    const float* gate_W2 = (const float*)d_in[28];
    const float* gate_b2 = (const float*)d_in[29];
    const float* reg_W1  = (const float*)d_in[30];
    const float* reg_b1  = (const float*)d_in[31];
    const float* reg_W2  = (const float*)d_in[32];
    const float* reg_b2  = (const float*)d_in[33];

    const int* srcArr = ei;            // row 0
    const int* dstArr = ei + N_EDGES;  // row 1

    float* ws = (float*)d_ws;
    size_t off = 0;
    auto alloc = [&](size_t nf) { float* p = ws + off; off += (nf + 63) & ~(size_t)63; return p; };
    float* xl        = alloc((size_t)N_NODES * FEAT);
    float* xr        = alloc((size_t)N_NODES * FEAT);
    float* h         = alloc((size_t)N_NODES * FEAT);
    float* loop_attr = alloc((size_t)N_NODES * ED_DIM);
    float* gpool     = alloc((size_t)BATCH * FEAT);
    int* ibase  = (int*)(ws + off);
    int* deg    = ibase;
    int* fill   = ibase + N_NODES;
    int* rowptr = ibase + 2 * N_NODES;            // N+1 ints
    int* bsum   = ibase + 3 * N_NODES + 64;
    int* boff   = bsum + 256;
    int2* elist2 = (int2*)(boff + 256);           // ETOT int2

    // aliases at disjoint lifetimes
    float* ghid = xl;                       // after L3 gat, xl is dead
    float* gate = xr;

    hipMemsetAsync(deg, 0, (size_t)2 * N_NODES * sizeof(int), stream);

    // CSR build, then self-loop mean attrs from CSR
    k_deg<<<(ETOT + 255) / 256, 256, 0, stream>>>(dstArr, deg);
    k_scan1<<<NCHUNK, 256, 0, stream>>>(deg, bsum);
    k_scan2<<<1, 256, 0, stream>>>(bsum, boff, rowptr);
    k_scan3<<<NCHUNK, 256, 0, stream>>>(deg, boff, rowptr);
    k_fill<<<(ETOT + 255) / 256, 256, 0, stream>>>(srcArr, dstArr, rowptr, fill, elist2);
    k_loop_csr<<<(N_NODES * ED_DIM + 255) / 256, 256, 0, stream>>>(elist2, rowptr, ea, loop_attr);

    // layer 1 (in: x [N,128])
    launch_gemm(x, c1_Wl, c1_bl, xl, N_NODES, FEAT, IN_DIM, 0, stream);
    launch_gemm(x, c1_Wr, c1_br, xr, N_NODES, FEAT, IN_DIM, 0, stream);
    k_gat<4, 1><<<N_NODES / 4, 256, 0, stream>>>(xl, xr, ea, loop_attr, elist2, rowptr,
                                                 c1_We, c1_att, c1_bias, h);
    // layer 2
    launch_gemm(h, c2_Wl, c2_bl, xl, N_NODES, FEAT, FEAT, 0, stream);
    launch_gemm(h, c2_Wr, c2_br, xr, N_NODES, FEAT, FEAT, 0, stream);
    k_gat<4, 1><<<N_NODES / 4, 256, 0, stream>>>(xl, xr, ea, loop_attr, elist2, rowptr,
                                                 c2_We, c2_att, c2_bias, h);
    // layer 3 (heads=1, no relu)
    launch_gemm(h, c3_Wl, c3_bl, xl, N_NODES, FEAT, FEAT, 0, stream);
    launch_gemm(h, c3_Wr, c3_br, xr, N_NODES, FEAT, FEAT, 0, stream);
    k_gat<1, 0><<<N_NODES / 4, 256, 0, stream>>>(xl, xr, ea, loop_attr, elist2, rowptr,
                                                 c3_We, c3_att, c3_bias, h);

    // pooling + head
    launch_gemm(h, gate_W1, gate_b1, ghid, N_NODES, 128, FEAT, 1, stream);
    k_gate_score<<<N_NODES / 4, 256, 0, stream>>>(ghid, gate_W2, gate_b2, gate);
    k_pool<<<BATCH, 256, 0, stream>>>(gate, h, batch, gpool);
    k_reg<<<BATCH, 128, 0, stream>>>(gpool, reg_W1, reg_b1, reg_W2, reg_b2, (float*)d_out);
}

// Round 8
// 1211.494 us; speedup vs baseline: 1.5816x; 1.1804x over previous
//
#include <hip/hip_runtime.h>
#include <math.h>

constexpr int N_NODES = 40000;
constexpr int N_EDGES = 500000;
constexpr int ETOT    = N_EDGES + N_NODES;
constexpr int IN_DIM  = 128;
constexpr int ED_DIM  = 16;
constexpr int FEAT    = 256;   // H*C for every layer
constexpr int BATCH   = 128;
constexpr float NEG   = 0.2f;
constexpr int NCHUNK  = (N_NODES + 255) / 256;  // 157

// ---------------- CSR build (by dst, incl. self loops) ----------------
__global__ __launch_bounds__(256) void k_deg(const int* __restrict__ dst, int* __restrict__ deg)
{
    int e = blockIdx.x * 256 + threadIdx.x;
    if (e >= ETOT) return;
    int v = e < N_EDGES ? dst[e] : e - N_EDGES;
    atomicAdd(&deg[v], 1);
}

__global__ __launch_bounds__(256) void k_scan1(const int* __restrict__ deg, int* __restrict__ bsum)
{
    __shared__ int s[256];
    int t = threadIdx.x;
    int idx = blockIdx.x * 256 + t;
    s[t] = idx < N_NODES ? deg[idx] : 0;
    __syncthreads();
    for (int st = 128; st; st >>= 1) { if (t < st) s[t] += s[t + st]; __syncthreads(); }
    if (t == 0) bsum[blockIdx.x] = s[0];
}

__global__ __launch_bounds__(256) void k_scan2(const int* __restrict__ bsum,
    int* __restrict__ boff, int* __restrict__ rowptr)
{
    __shared__ int s[256];
    int t = threadIdx.x;
    int v = t < NCHUNK ? bsum[t] : 0;
    s[t] = v;
    __syncthreads();
    for (int off = 1; off < 256; off <<= 1) {
        int x = (t >= off) ? s[t - off] : 0;
        __syncthreads();
        s[t] += x;
        __syncthreads();
    }
    if (t < NCHUNK) boff[t] = s[t] - v;
    if (t == 0) rowptr[N_NODES] = ETOT;
}

__global__ __launch_bounds__(256) void k_scan3(const int* __restrict__ deg,
    const int* __restrict__ boff, int* __restrict__ rowptr)
{
    __shared__ int s[256];
    int t = threadIdx.x;
    int idx = blockIdx.x * 256 + t;
    int v = idx < N_NODES ? deg[idx] : 0;
    s[t] = v;
    __syncthreads();
    for (int off = 1; off < 256; off <<= 1) {
        int x = (t >= off) ? s[t - off] : 0;
        __syncthreads();
        s[t] += x;
        __syncthreads();
    }
    if (idx < N_NODES) rowptr[idx] = boff[blockIdx.x] + s[t] - v;
}

// elist2[pos] = (src, eid)
__global__ __launch_bounds__(256) void k_fill(const int* __restrict__ srcA, const int* __restrict__ dst,
    const int* __restrict__ rowptr, int* __restrict__ fill, int2* __restrict__ elist2)
{
    int e = blockIdx.x * 256 + threadIdx.x;
    if (e >= ETOT) return;
    int v = e < N_EDGES ? dst[e]  : e - N_EDGES;
    int s = e < N_EDGES ? srcA[e] : e - N_EDGES;
    int pos = rowptr[v] + atomicAdd(&fill[v], 1);
    elist2[pos] = make_int2(s, e);
}

// ---------------- self-loop mean edge attr via CSR (no atomics) ----------------
__global__ __launch_bounds__(256) void k_loop_csr(const int2* __restrict__ elist2,
    const int* __restrict__ rowptr, const float* __restrict__ ea, float* __restrict__ loop_attr)
{
    int t = blockIdx.x * 256 + threadIdx.x;
    if (t >= N_NODES * ED_DIM) return;
    int n = t >> 4, d = t & 15;
    int p0 = rowptr[n], p1 = rowptr[n + 1];
    float s = 0.f; int c = 0;
    for (int p = p0; p < p1; ++p) {
        int e = elist2[p].y;
        if (e < N_EDGES) { s += ea[(size_t)e * ED_DIM + d]; ++c; }
    }
    loop_attr[t] = s / (float)(c > 0 ? c : 1);
}

// ---------------- fp32 GEMM (R4 version): 128x128 tile, reg prefetch ----------------
__global__ __launch_bounds__(256) void k_gemm(const float* __restrict__ A, const float* __restrict__ W,
    const float* __restrict__ bias, float* __restrict__ C, int M, int N, int K, int act)
{
    __shared__ float As[16][136];   // [k][m]
    __shared__ float Bs[16][136];   // [k][n]
    int t = threadIdx.x;
    int bm = blockIdx.x * 128, bn = blockIdx.y * 128;
    int tr = t >> 4, tc = t & 15;
    int mr0 = tr * 8, nc0 = tc * 4;

    int ar0 = t >> 1, ak0 = (t & 1) << 3;
    int bk0 = t >> 5, bn0 = (t & 31) << 2;

    float acc[8][8] = {};

    int r0 = bm + ar0; r0 = r0 < M ? r0 : M - 1;
    float4 avA = *(const float4*)(A + (size_t)r0 * K + ak0);
    float4 avB = *(const float4*)(A + (size_t)r0 * K + ak0 + 4);
    float4 bvA = *(const float4*)(W + (size_t)bk0 * N + bn + bn0);
    float4 bvB = *(const float4*)(W + (size_t)(bk0 + 8) * N + bn + bn0);

    for (int k0 = 0; k0 < K; k0 += 16) {
        __syncthreads();
        As[ak0 + 0][ar0] = avA.x; As[ak0 + 1][ar0] = avA.y;
        As[ak0 + 2][ar0] = avA.z; As[ak0 + 3][ar0] = avA.w;
        As[ak0 + 4][ar0] = avB.x; As[ak0 + 5][ar0] = avB.y;
        As[ak0 + 6][ar0] = avB.z; As[ak0 + 7][ar0] = avB.w;
        *(float4*)&Bs[bk0][bn0]     = bvA;
        *(float4*)&Bs[bk0 + 8][bn0] = bvB;
        __syncthreads();
        if (k0 + 16 < K) {
            avA = *(const float4*)(A + (size_t)r0 * K + k0 + 16 + ak0);
            avB = *(const float4*)(A + (size_t)r0 * K + k0 + 16 + ak0 + 4);
            bvA = *(const float4*)(W + (size_t)(k0 + 16 + bk0) * N + bn + bn0);
            bvB = *(const float4*)(W + (size_t)(k0 + 24 + bk0) * N + bn + bn0);
        }
        #pragma unroll
        for (int k = 0; k < 16; ++k) {
            float4 a0 = *(const float4*)&As[k][mr0];
            float4 a1 = *(const float4*)&As[k][mr0 + 4];
            float4 b0 = *(const float4*)&Bs[k][nc0];
            float4 b1 = *(const float4*)&Bs[k][64 + nc0];
            float am[8] = {a0.x, a0.y, a0.z, a0.w, a1.x, a1.y, a1.z, a1.w};
            float bv[8] = {b0.x, b0.y, b0.z, b0.w, b1.x, b1.y, b1.z, b1.w};
            #pragma unroll
            for (int i = 0; i < 8; ++i)
                #pragma unroll
                for (int j = 0; j < 8; ++j)
                    acc[i][j] = fmaf(am[i], bv[j], acc[i][j]);
        }
    }

    float bb[8];
    #pragma unroll
    for (int j = 0; j < 4; ++j) { bb[j] = bias[bn + nc0 + j]; bb[j + 4] = bias[bn + 64 + nc0 + j]; }
    #pragma unroll
    for (int i = 0; i < 8; ++i) {
        int row = bm + mr0 + i;
        if (row >= M) break;
        float4 o0, o1;
        o0.x = acc[i][0] + bb[0]; o0.y = acc[i][1] + bb[1];
        o0.z = acc[i][2] + bb[2]; o0.w = acc[i][3] + bb[3];
        o1.x = acc[i][4] + bb[4]; o1.y = acc[i][5] + bb[5];
        o1.z = acc[i][6] + bb[6]; o1.w = acc[i][7] + bb[7];
        if (act) {
            o0.x = fmaxf(o0.x, 0.f); o0.y = fmaxf(o0.y, 0.f); o0.z = fmaxf(o0.z, 0.f); o0.w = fmaxf(o0.w, 0.f);
            o1.x = fmaxf(o1.x, 0.f); o1.y = fmaxf(o1.y, 0.f); o1.z = fmaxf(o1.z, 0.f); o1.w = fmaxf(o1.w, 0.f);
        }
        *(float4*)(C + (size_t)row * N + bn + nc0)      = o0;
        *(float4*)(C + (size_t)row * N + bn + 64 + nc0) = o1;
    }
}

static void launch_gemm(const float* A, const float* W, const float* bias, float* C,
                        int M, int N, int K, int act, hipStream_t stream)
{
    dim3 grid((M + 127) / 128, N / 128);
    k_gemm<<<grid, 256, 0, stream>>>(A, W, bias, C, M, N, K, act);
}

// ---------------- fused GATv2 v2: one wave per dst node ----------------
// Channel map: c(j) = 4*lane + j. Quarter q = lane>>4 covers channels
// [q*64, q*64+64) == head q when H=4. float4 loads for xl/xr/weR/out.
// (src,e) scalarized via readfirstlane -> SALU addressing, s_load-able ea.

#define XELOAD(s) do {                                                                \
    int src_ = __builtin_amdgcn_readfirstlane(eS[s].x);                               \
    int e_   = __builtin_amdgcn_readfirstlane(eS[s].y);                               \
    const float4* eb4_ = reinterpret_cast<const float4*>(                             \
        (e_ < N_EDGES) ? ea + (size_t)e_ * ED_DIM                                     \
                       : loop_attr + (size_t)src_ * ED_DIM);                          \
    evS[s][0] = eb4_[0]; evS[s][1] = eb4_[1];                                         \
    evS[s][2] = eb4_[2]; evS[s][3] = eb4_[3];                                         \
    xlvS[s] = *(const float4*)(xl + (size_t)src_ * FEAT + base);                      \
} while (0)

#define COMPUTE(s) do {                                                               \
    float ef0_ = 0.f, ef1_ = 0.f, ef2_ = 0.f, ef3_ = 0.f;                             \
    const float* ed_ = (const float*)evS[s];                                          \
    _Pragma("unroll")                                                                 \
    for (int d_ = 0; d_ < ED_DIM; ++d_) {                                             \
        float a_ = ed_[d_];                                                           \
        ef0_ = fmaf(a_, weR[d_].x, ef0_); ef1_ = fmaf(a_, weR[d_].y, ef1_);           \
        ef2_ = fmaf(a_, weR[d_].z, ef2_); ef3_ = fmaf(a_, weR[d_].w, ef3_);           \
    }                                                                                 \
    float s0_ = xlvS[s].x + xrv.x + ef0_;                                             \
    float s1_ = xlvS[s].y + xrv.y + ef1_;                                             \
    float s2_ = xlvS[s].z + xrv.z + ef2_;                                             \
    float s3_ = xlvS[s].w + xrv.w + ef3_;                                             \
    s0_ = fmaxf(s0_, 0.f) + NEG * fminf(s0_, 0.f);                                    \
    s1_ = fmaxf(s1_, 0.f) + NEG * fminf(s1_, 0.f);                                    \
    s2_ = fmaxf(s2_, 0.f) + NEG * fminf(s2_, 0.f);                                    \
    s3_ = fmaxf(s3_, 0.f) + NEG * fminf(s3_, 0.f);                                    \
    float l_ = fmaf(s0_, attR.x, fmaf(s1_, attR.y, fmaf(s2_, attR.z, s3_ * attR.w))); \
    l_ += __shfl_xor(l_, 1, 64);                                                      \
    l_ += __shfl_xor(l_, 2, 64);                                                      \
    l_ += __shfl_xor(l_, 4, 64);                                                      \
    l_ += __shfl_xor(l_, 8, 64);                                                      \
    if (H == 1) { l_ += __shfl_xor(l_, 16, 64); l_ += __shfl_xor(l_, 32, 64); }       \
    float nm_ = fmaxf(m, l_);                                                         \
    float sc_ = __expf(m - nm_);                                                      \
    float w_  = __expf(l_ - nm_);                                                     \
    z = fmaf(z, sc_, w_);                                                             \
    m = nm_;                                                                          \
    acc.x = fmaf(acc.x, sc_, w_ * xlvS[s].x);                                         \
    acc.y = fmaf(acc.y, sc_, w_ * xlvS[s].y);                                         \
    acc.z = fmaf(acc.z, sc_, w_ * xlvS[s].z);                                         \
    acc.w = fmaf(acc.w, sc_, w_ * xlvS[s].w);                                         \
} while (0)

template <int H, int RELU>
__global__ __launch_bounds__(256, 4) void k_gat(
    const float* __restrict__ xl, const float* __restrict__ xr,
    const float* __restrict__ ea, const float* __restrict__ loop_attr,
    const int2* __restrict__ elist2, const int* __restrict__ rowptr,
    const float* __restrict__ We, const float* __restrict__ att,
    const float* __restrict__ bias, float* __restrict__ out)
{
    int t = threadIdx.x;
    int lane = t & 63;
    int n = __builtin_amdgcn_readfirstlane(blockIdx.x * 4 + (t >> 6));
    int base = lane * 4;

    float4 weR[ED_DIM];
    #pragma unroll
    for (int d = 0; d < ED_DIM; ++d)
        weR[d] = *(const float4*)(We + d * FEAT + base);

    float4 attR = *(const float4*)(att + base);
    float4 xrv  = *(const float4*)(xr + (size_t)n * FEAT + base);

    float m = -INFINITY, z = 0.f;
    float4 acc = {0.f, 0.f, 0.f, 0.f};

    int p0 = rowptr[n], p1 = rowptr[n + 1];   // p1 > p0 guaranteed (self-loop)
    int pe = p1 - 1;

    int2   eS[2];
    float4 evS[2][4];
    float4 xlvS[2];

    eS[0] = elist2[p0];
    { int pc = p0 + 1 > pe ? pe : p0 + 1; eS[1] = elist2[pc]; }
    XELOAD(0);

    int p = p0;
    while (true) {
        XELOAD(1);
        { int pn = p + 2 > pe ? pe : p + 2; eS[0] = elist2[pn]; }
        COMPUTE(0);
        if (++p >= p1) break;
        XELOAD(0);
        { int pn = p + 2 > pe ? pe : p + 2; eS[1] = elist2[pn]; }
        COMPUTE(1);
        if (++p >= p1) break;
    }

    float inv = 1.0f / (z + 1e-16f);
    float4 bs = *(const float4*)(bias + base);
    float4 o;
    o.x = fmaf(acc.x, inv, bs.x);
    o.y = fmaf(acc.y, inv, bs.y);
    o.z = fmaf(acc.z, inv, bs.z);
    o.w = fmaf(acc.w, inv, bs.w);
    if (RELU) {
        o.x = fmaxf(o.x, 0.f); o.y = fmaxf(o.y, 0.f);
        o.z = fmaxf(o.z, 0.f); o.w = fmaxf(o.w, 0.f);
    }
    *(float4*)(out + (size_t)n * FEAT + base) = o;
}

// ---------------- gate score: gate[n] = ghid[n,:] @ W2 + b2 ----------------
__global__ __launch_bounds__(256) void k_gate_score(const float* __restrict__ ghid,
    const float* __restrict__ W2, const float* __restrict__ b2, float* __restrict__ gate)
{
    int lane = threadIdx.x & 63;
    int n = blockIdx.x * 4 + (threadIdx.x >> 6);
    float v = ghid[(size_t)n * 128 + lane] * W2[lane] + ghid[(size_t)n * 128 + lane + 64] * W2[lane + 64];
    #pragma unroll
    for (int off = 32; off > 0; off >>= 1) v += __shfl_xor(v, off, 64);
    if (lane == 0) gate[n] = v + b2[0];
}

// ---------------- attentional pooling: one block per batch segment ----------------
__device__ __forceinline__ int lbound(const int* a, int n, int v)
{
    int lo = 0, hi = n;
    while (lo < hi) { int mid = (lo + hi) >> 1; if (a[mid] < v) lo = mid + 1; else hi = mid; }
    return lo;
}

__global__ __launch_bounds__(256) void k_pool(const float* __restrict__ gate,
    const float* __restrict__ h, const int* __restrict__ batch, float* __restrict__ g)
{
    int b = blockIdx.x;
    int t = threadIdx.x;
    __shared__ float red[256];
    int start = lbound(batch, N_NODES, b);
    int end   = lbound(batch, N_NODES, b + 1);

    float mx = -INFINITY;
    for (int n = start + t; n < end; n += 256) mx = fmaxf(mx, gate[n]);
    red[t] = mx; __syncthreads();
    for (int s = 128; s; s >>= 1) { if (t < s) red[t] = fmaxf(red[t], red[t + s]); __syncthreads(); }
    float m = red[0];
    __syncthreads();

    float zs = 0.f;
    for (int n = start + t; n < end; n += 256) zs += __expf(gate[n] - m);
    red[t] = zs; __syncthreads();
    for (int s = 128; s; s >>= 1) { if (t < s) red[t] += red[t + s]; __syncthreads(); }
    float z = red[0];

    float gs = 0.f;
    for (int n = start; n < end; ++n) gs += __expf(gate[n] - m) * h[(size_t)n * FEAT + t];
    g[b * FEAT + t] = gs / (z + 1e-16f);
}

// ---------------- regression head: per-batch tiny MLP ----------------
__global__ __launch_bounds__(128) void k_reg(const float* __restrict__ g,
    const float* __restrict__ W1, const float* __restrict__ b1,
    const float* __restrict__ W2, const float* __restrict__ b2, float* __restrict__ out)
{
    int b = blockIdx.x, t = threadIdx.x;
    __shared__ float sg[FEAT];
    sg[t] = g[b * FEAT + t];
    sg[t + 128] = g[b * FEAT + t + 128];
    __syncthreads();
    float hv = b1[t];
    for (int k = 0; k < FEAT; ++k) hv += sg[k] * W1[k * 128 + t];
    hv = fmaxf(hv, 0.f);
    __shared__ float p0s[128], p1s[128];
    p0s[t] = hv * W2[t * 2 + 0];
    p1s[t] = hv * W2[t * 2 + 1];
    __syncthreads();
    for (int s = 64; s; s >>= 1) {
        if (t < s) { p0s[t] += p0s[t + s]; p1s[t] += p1s[t + s]; }
        __syncthreads();
    }
    if (t == 0) { out[b * 2 + 0] = p0s[0] + b2[0]; out[b * 2 + 1] = p1s[0] + b2[1]; }
}

// ---------------- launch ----------------
extern "C" void kernel_launch(void* const* d_in, const int* in_sizes, int n_in,
                              void* d_out, int out_size, void* d_ws, size_t ws_size,
                              hipStream_t stream)
{
    const float* x       = (const float*)d_in[0];
    const int*   ei      = (const int*)d_in[1];   // [2,E]
    const float* ea      = (const float*)d_in[2];
    const int*   batch   = (const int*)d_in[3];
    const float* c1_Wl   = (const float*)d_in[5];
    const float* c1_bl   = (const float*)d_in[6];
    const float* c1_Wr   = (const float*)d_in[7];
    const float* c1_br   = (const float*)d_in[8];
    const float* c1_We   = (const float*)d_in[9];
    const float* c1_att  = (const float*)d_in[10];
    const float* c1_bias = (const float*)d_in[11];
    const float* c2_Wl   = (const float*)d_in[12];
    const float* c2_bl   = (const float*)d_in[13];
    const float* c2_Wr   = (const float*)d_in[14];
    const float* c2_br   = (const float*)d_in[15];
    const float* c2_We   = (const float*)d_in[16];
    const float* c2_att  = (const float*)d_in[17];
    const float* c2_bias = (const float*)d_in[18];
    const float* c3_Wl   = (const float*)d_in[19];
    const float* c3_bl   = (const float*)d_in[20];
    const float* c3_Wr   = (const float*)d_in[21];
    const float* c3_br   = (const float*)d_in[22];
    const float* c3_We   = (const float*)d_in[23];
    const float* c3_att  = (const float*)d_in[24];
    const float* c3_bias = (const float*)d_in[25];
    const float* gate_W1 = (const float*)d_in[26];
    const float* gate_b1 = (const float*)d_in[27];
    const float* gate_W2 = (const float*)d_in[28];
    const float* gate_b2 = (const float*)d_in[29];
    const float* reg_W1  = (const float*)d_in[30];
    const float* reg_b1  = (const float*)d_in[31];
    const float* reg_W2  = (const float*)d_in[32];
    const float* reg_b2  = (const float*)d_in[33];

    const int* srcArr = ei;            // row 0
    const int* dstArr = ei + N_EDGES;  // row 1

    float* ws = (float*)d_ws;
    size_t off = 0;
    auto alloc = [&](size_t nf) { float* p = ws + off; off += (nf + 63) & ~(size_t)63; return p; };
    float* xl        = alloc((size_t)N_NODES * FEAT);
    float* xr        = alloc((size_t)N_NODES * FEAT);
    float* h         = alloc((size_t)N_NODES * FEAT);
    float* loop_attr = alloc((size_t)N_NODES * ED_DIM);
    float* gpool     = alloc((size_t)BATCH * FEAT);
    int* ibase  = (int*)(ws + off);
    int* deg    = ibase;
    int* fill   = ibase + N_NODES;
    int* rowptr = ibase + 2 * N_NODES;            // N+1 ints
    int* bsum   = ibase + 3 * N_NODES + 64;
    int* boff   = bsum + 256;
    int2* elist2 = (int2*)(boff + 256);           // ETOT int2

    // aliases at disjoint lifetimes
    float* ghid = xl;                       // after L3 gat, xl is dead
    float* gate = xr;

    hipMemsetAsync(deg, 0, (size_t)2 * N_NODES * sizeof(int), stream);

    // CSR build, then self-loop mean attrs from CSR
    k_deg<<<(ETOT + 255) / 256, 256, 0, stream>>>(dstArr, deg);
    k_scan1<<<NCHUNK, 256, 0, stream>>>(deg, bsum);
    k_scan2<<<1, 256, 0, stream>>>(bsum, boff, rowptr);
    k_scan3<<<NCHUNK, 256, 0, stream>>>(deg, boff, rowptr);
    k_fill<<<(ETOT + 255) / 256, 256, 0, stream>>>(srcArr, dstArr, rowptr, fill, elist2);
    k_loop_csr<<<(N_NODES * ED_DIM + 255) / 256, 256, 0, stream>>>(elist2, rowptr, ea, loop_attr);

    // layer 1 (in: x [N,128])
    launch_gemm(x, c1_Wl, c1_bl, xl, N_NODES, FEAT, IN_DIM, 0, stream);
    launch_gemm(x, c1_Wr, c1_br, xr, N_NODES, FEAT, IN_DIM, 0, stream);
    k_gat<4, 1><<<N_NODES / 4, 256, 0, stream>>>(xl, xr, ea, loop_attr, elist2, rowptr,
                                                 c1_We, c1_att, c1_bias, h);
    // layer 2
    launch_gemm(h, c2_Wl, c2_bl, xl, N_NODES, FEAT, FEAT, 0, stream);
    launch_gemm(h, c2_Wr, c2_br, xr, N_NODES, FEAT, FEAT, 0, stream);
    k_gat<4, 1><<<N_NODES / 4, 256, 0, stream>>>(xl, xr, ea, loop_attr, elist2, rowptr,
                                                 c2_We, c2_att, c2_bias, h);
    // layer 3 (heads=1, no relu)
    launch_gemm(h, c3_Wl, c3_bl, xl, N_NODES, FEAT, FEAT, 0, stream);
    launch_gemm(h, c3_Wr, c3_br, xr, N_NODES, FEAT, FEAT, 0, stream);
    k_gat<1, 0><<<N_NODES / 4, 256, 0, stream>>>(xl, xr, ea, loop_attr, elist2, rowptr,
                                                 c3_We, c3_att, c3_bias, h);

    // pooling + head
    launch_gemm(h, gate_W1, gate_b1, ghid, N_NODES, 128, FEAT, 1, stream);
    k_gate_score<<<N_NODES / 4, 256, 0, stream>>>(ghid, gate_W2, gate_b2, gate);
    k_pool<<<BATCH, 256, 0, stream>>>(gate, h, batch, gpool);
    k_reg<<<BATCH, 128, 0, stream>>>(gpool, reg_W1, reg_b1, reg_W2, reg_b2, (float*)d_out);
}

// Round 9
// 1121.723 us; speedup vs baseline: 1.7081x; 1.0800x over previous
//
#include <hip/hip_runtime.h>
#include <math.h>

constexpr int N_NODES = 40000;
constexpr int N_EDGES = 500000;
constexpr int ETOT    = N_EDGES + N_NODES;
constexpr int IN_DIM  = 128;
constexpr int ED_DIM  = 16;
constexpr int FEAT    = 256;   // H*C for every layer
constexpr int BATCH   = 128;
constexpr float NEG   = 0.2f;
constexpr int NCHUNK  = (N_NODES + 255) / 256;  // 157

typedef __bf16 bf16x8 __attribute__((ext_vector_type(8)));
typedef float  f32x4  __attribute__((ext_vector_type(4)));

// ---------------- CSR build (by dst, incl. self loops) ----------------
__global__ __launch_bounds__(256) void k_deg(const int* __restrict__ dst, int* __restrict__ deg)
{
    int e = blockIdx.x * 256 + threadIdx.x;
    if (e >= ETOT) return;
    int v = e < N_EDGES ? dst[e] : e - N_EDGES;
    atomicAdd(&deg[v], 1);
}

__global__ __launch_bounds__(256) void k_scan1(const int* __restrict__ deg, int* __restrict__ bsum)
{
    __shared__ int s[256];
    int t = threadIdx.x;
    int idx = blockIdx.x * 256 + t;
    s[t] = idx < N_NODES ? deg[idx] : 0;
    __syncthreads();
    for (int st = 128; st; st >>= 1) { if (t < st) s[t] += s[t + st]; __syncthreads(); }
    if (t == 0) bsum[blockIdx.x] = s[0];
}

__global__ __launch_bounds__(256) void k_scan2(const int* __restrict__ bsum,
    int* __restrict__ boff, int* __restrict__ rowptr)
{
    __shared__ int s[256];
    int t = threadIdx.x;
    int v = t < NCHUNK ? bsum[t] : 0;
    s[t] = v;
    __syncthreads();
    for (int off = 1; off < 256; off <<= 1) {
        int x = (t >= off) ? s[t - off] : 0;
        __syncthreads();
        s[t] += x;
        __syncthreads();
    }
    if (t < NCHUNK) boff[t] = s[t] - v;
    if (t == 0) rowptr[N_NODES] = ETOT;
}

__global__ __launch_bounds__(256) void k_scan3(const int* __restrict__ deg,
    const int* __restrict__ boff, int* __restrict__ rowptr)
{
    __shared__ int s[256];
    int t = threadIdx.x;
    int idx = blockIdx.x * 256 + t;
    int v = idx < N_NODES ? deg[idx] : 0;
    s[t] = v;
    __syncthreads();
    for (int off = 1; off < 256; off <<= 1) {
        int x = (t >= off) ? s[t - off] : 0;
        __syncthreads();
        s[t] += x;
        __syncthreads();
    }
    if (idx < N_NODES) rowptr[idx] = boff[blockIdx.x] + s[t] - v;
}

// elist2[pos] = (src, eid)
__global__ __launch_bounds__(256) void k_fill(const int* __restrict__ srcA, const int* __restrict__ dst,
    const int* __restrict__ rowptr, int* __restrict__ fill, int2* __restrict__ elist2)
{
    int e = blockIdx.x * 256 + threadIdx.x;
    if (e >= ETOT) return;
    int v = e < N_EDGES ? dst[e]  : e - N_EDGES;
    int s = e < N_EDGES ? srcA[e] : e - N_EDGES;
    int pos = rowptr[v] + atomicAdd(&fill[v], 1);
    elist2[pos] = make_int2(s, e);
}

// ---------------- self-loop mean edge attr via CSR (no atomics) ----------------
__global__ __launch_bounds__(256) void k_loop_csr(const int2* __restrict__ elist2,
    const int* __restrict__ rowptr, const float* __restrict__ ea, float* __restrict__ loop_attr)
{
    int t = blockIdx.x * 256 + threadIdx.x;
    if (t >= N_NODES * ED_DIM) return;
    int n = t >> 4, d = t & 15;
    int p0 = rowptr[n], p1 = rowptr[n + 1];
    float s = 0.f; int c = 0;
    for (int p = p0; p < p1; ++p) {
        int e = elist2[p].y;
        if (e < N_EDGES) { s += ea[(size_t)e * ED_DIM + d]; ++c; }
    }
    loop_attr[t] = s / (float)(c > 0 ? c : 1);
}

// ---------------- split fp32 -> bf16 hi/lo ----------------
__device__ __forceinline__ void bsplit(float x, unsigned short& h, unsigned short& l)
{
    unsigned u = __float_as_uint(x);
    unsigned r = (u + 0x7FFFu + ((u >> 16) & 1u)) >> 16;
    h = (unsigned short)r;
    float rem = x - __uint_as_float(r << 16);
    unsigned u2 = __float_as_uint(rem);
    l = (unsigned short)((u2 + 0x7FFFu + ((u2 >> 16) & 1u)) >> 16);
}

__global__ __launch_bounds__(256) void k_cvt(const float* __restrict__ X,
    unsigned short* __restrict__ Xh, unsigned short* __restrict__ Xl, int n4)
{
    int i = blockIdx.x * 256 + threadIdx.x;
    if (i >= n4) return;
    float4 v = ((const float4*)X)[i];
    ushort4 h, l;
    bsplit(v.x, h.x, l.x);
    bsplit(v.y, h.y, l.y);
    bsplit(v.z, h.z, l.z);
    bsplit(v.w, h.w, l.w);
    ((ushort4*)Xh)[i] = h;
    ((ushort4*)Xl)[i] = l;
}

// W[K][N] fp32 -> WhT/WlT [N][K] bf16 (transposed for B-fragment b128 reads)
__global__ __launch_bounds__(256) void k_cvtT(const float* __restrict__ W,
    unsigned short* __restrict__ WhT, unsigned short* __restrict__ WlT, int K, int N)
{
    int i = blockIdx.x * 256 + threadIdx.x;
    if (i >= K * N) return;
    int k = i / N, n = i - k * N;
    unsigned short h, l;
    bsplit(W[i], h, l);
    WhT[(size_t)n * K + k] = h;
    WlT[(size_t)n * K + k] = l;
}

// ---------------- split-bf16 MFMA GEMM: C = Ah·Bh + Ah·Bl + Al·Bh + bias (+relu) ----------------
// 128x128 tile, 4 waves; wave (mh,nh) computes 64x64 = 4x4 MFMA 16x16x32 tiles.
// LDS is fragment-major: slot s = tile*64 + lane, 16 B each -> conflict-free b128 both ways.
// A frag: lane holds A[m=lane&15][k=(lane>>4)*8+j]; B frag: B^T[n=lane&15][k=(lane>>4)*8+j];
// D: col=lane&15, row=(lane>>4)*4+i.
__global__ __launch_bounds__(256) void k_mgemm(
    const unsigned short* __restrict__ Ah, const unsigned short* __restrict__ Al,
    const unsigned short* __restrict__ BhT, const unsigned short* __restrict__ BlT,
    const float* __restrict__ bias, float* __restrict__ C,
    int M, int N, int K, int act)
{
    __shared__ uint4 sAh[512], sAl[512], sBh[512], sBl[512];   // 8 KB each

    int t = threadIdx.x;
    int bm = blockIdx.x * 128, bn = blockIdx.y * 128;
    int lane = t & 63;
    int w = t >> 6;
    int mh = w >> 1, nh = w & 1;

    // staging coords: slots s0=t (tiles 0..3), s1=t+256 (tiles 4..7)
    int sT = t >> 6, sq = (t >> 4) & 3, slm = t & 15;
    int am0 = bm + sT * 16 + slm;        am0 = am0 < M ? am0 : M - 1;
    int am1 = bm + (sT + 4) * 16 + slm;  am1 = am1 < M ? am1 : M - 1;
    int bn0 = bn + sT * 16 + slm;
    int bn1 = bn + (sT + 4) * 16 + slm;
    size_t aoff0 = (size_t)am0 * K + sq * 8;
    size_t aoff1 = (size_t)am1 * K + sq * 8;
    size_t boff0 = (size_t)bn0 * K + sq * 8;
    size_t boff1 = (size_t)bn1 * K + sq * 8;

    f32x4 acc[4][4] = {};

    uint4 rAh0 = *(const uint4*)(Ah + aoff0),  rAh1 = *(const uint4*)(Ah + aoff1);
    uint4 rAl0 = *(const uint4*)(Al + aoff0),  rAl1 = *(const uint4*)(Al + aoff1);
    uint4 rBh0 = *(const uint4*)(BhT + boff0), rBh1 = *(const uint4*)(BhT + boff1);
    uint4 rBl0 = *(const uint4*)(BlT + boff0), rBl1 = *(const uint4*)(BlT + boff1);

    int nk = K >> 5;
    for (int ks = 0; ks < nk; ++ks) {
        sAh[t] = rAh0; sAh[t + 256] = rAh1;
        sAl[t] = rAl0; sAl[t + 256] = rAl1;
        sBh[t] = rBh0; sBh[t + 256] = rBh1;
        sBl[t] = rBl0; sBl[t + 256] = rBl1;
        __syncthreads();
        if (ks + 1 < nk) {
            int k8 = (ks + 1) << 5;   // ushort offset
            rAh0 = *(const uint4*)(Ah + aoff0 + k8);  rAh1 = *(const uint4*)(Ah + aoff1 + k8);
            rAl0 = *(const uint4*)(Al + aoff0 + k8);  rAl1 = *(const uint4*)(Al + aoff1 + k8);
            rBh0 = *(const uint4*)(BhT + boff0 + k8); rBh1 = *(const uint4*)(BhT + boff1 + k8);
            rBl0 = *(const uint4*)(BlT + boff0 + k8); rBl1 = *(const uint4*)(BlT + boff1 + k8);
        }
        bf16x8 fah[4], fal[4], fbh[4], fbl[4];
        #pragma unroll
        for (int mt = 0; mt < 4; ++mt) {
            fah[mt] = __builtin_bit_cast(bf16x8, sAh[(mh * 4 + mt) * 64 + lane]);
            fal[mt] = __builtin_bit_cast(bf16x8, sAl[(mh * 4 + mt) * 64 + lane]);
        }
        #pragma unroll
        for (int nt = 0; nt < 4; ++nt) {
            fbh[nt] = __builtin_bit_cast(bf16x8, sBh[(nh * 4 + nt) * 64 + lane]);
            fbl[nt] = __builtin_bit_cast(bf16x8, sBl[(nh * 4 + nt) * 64 + lane]);
        }
        #pragma unroll
        for (int mt = 0; mt < 4; ++mt)
            #pragma unroll
            for (int nt = 0; nt < 4; ++nt) {
                acc[mt][nt] = __builtin_amdgcn_mfma_f32_16x16x32_bf16(fah[mt], fbh[nt], acc[mt][nt], 0, 0, 0);
                acc[mt][nt] = __builtin_amdgcn_mfma_f32_16x16x32_bf16(fah[mt], fbl[nt], acc[mt][nt], 0, 0, 0);
                acc[mt][nt] = __builtin_amdgcn_mfma_f32_16x16x32_bf16(fal[mt], fbh[nt], acc[mt][nt], 0, 0, 0);
            }
        __syncthreads();
    }

    int q = lane >> 4, lm = lane & 15;
    #pragma unroll
    for (int nt = 0; nt < 4; ++nt) {
        int col = bn + nh * 64 + nt * 16 + lm;
        float bb = bias[col];
        #pragma unroll
        for (int mt = 0; mt < 4; ++mt) {
            #pragma unroll
            for (int i = 0; i < 4; ++i) {
                int row = bm + mh * 64 + mt * 16 + q * 4 + i;
                if (row < M) {
                    float o = acc[mt][nt][i] + bb;
                    if (act) o = fmaxf(o, 0.f);
                    C[(size_t)row * N + col] = o;
                }
            }
        }
    }
}

static void launch_mgemm(const unsigned short* Ah, const unsigned short* Al,
                         const unsigned short* BhT, const unsigned short* BlT,
                         const float* bias, float* C, int M, int N, int K, int act,
                         hipStream_t stream)
{
    dim3 grid((M + 127) / 128, N / 128);
    k_mgemm<<<grid, 256, 0, stream>>>(Ah, Al, BhT, BlT, bias, C, M, N, K, act);
}

// ---------------- fused GATv2 (R8 version, benched 165 us/layer) ----------------
#define XELOAD(s) do {                                                                \
    int src_ = __builtin_amdgcn_readfirstlane(eS[s].x);                               \
    int e_   = __builtin_amdgcn_readfirstlane(eS[s].y);                               \
    const float4* eb4_ = reinterpret_cast<const float4*>(                             \
        (e_ < N_EDGES) ? ea + (size_t)e_ * ED_DIM                                     \
                       : loop_attr + (size_t)src_ * ED_DIM);                          \
    evS[s][0] = eb4_[0]; evS[s][1] = eb4_[1];                                         \
    evS[s][2] = eb4_[2]; evS[s][3] = eb4_[3];                                         \
    xlvS[s] = *(const float4*)(xl + (size_t)src_ * FEAT + base);                      \
} while (0)

#define COMPUTE(s) do {                                                               \
    float ef0_ = 0.f, ef1_ = 0.f, ef2_ = 0.f, ef3_ = 0.f;                             \
    const float* ed_ = (const float*)evS[s];                                          \
    _Pragma("unroll")                                                                 \
    for (int d_ = 0; d_ < ED_DIM; ++d_) {                                             \
        float a_ = ed_[d_];                                                           \
        ef0_ = fmaf(a_, weR[d_].x, ef0_); ef1_ = fmaf(a_, weR[d_].y, ef1_);           \
        ef2_ = fmaf(a_, weR[d_].z, ef2_); ef3_ = fmaf(a_, weR[d_].w, ef3_);           \
    }                                                                                 \
    float s0_ = xlvS[s].x + xrv.x + ef0_;                                             \
    float s1_ = xlvS[s].y + xrv.y + ef1_;                                             \
    float s2_ = xlvS[s].z + xrv.z + ef2_;                                             \
    float s3_ = xlvS[s].w + xrv.w + ef3_;                                             \
    s0_ = fmaxf(s0_, 0.f) + NEG * fminf(s0_, 0.f);                                    \
    s1_ = fmaxf(s1_, 0.f) + NEG * fminf(s1_, 0.f);                                    \
    s2_ = fmaxf(s2_, 0.f) + NEG * fminf(s2_, 0.f);                                    \
    s3_ = fmaxf(s3_, 0.f) + NEG * fminf(s3_, 0.f);                                    \
    float l_ = fmaf(s0_, attR.x, fmaf(s1_, attR.y, fmaf(s2_, attR.z, s3_ * attR.w))); \
    l_ += __shfl_xor(l_, 1, 64);                                                      \
    l_ += __shfl_xor(l_, 2, 64);                                                      \
    l_ += __shfl_xor(l_, 4, 64);                                                      \
    l_ += __shfl_xor(l_, 8, 64);                                                      \
    if (H == 1) { l_ += __shfl_xor(l_, 16, 64); l_ += __shfl_xor(l_, 32, 64); }       \
    float nm_ = fmaxf(m, l_);                                                         \
    float sc_ = __expf(m - nm_);                                                      \
    float w_  = __expf(l_ - nm_);                                                     \
    z = fmaf(z, sc_, w_);                                                             \
    m = nm_;                                                                          \
    acc.x = fmaf(acc.x, sc_, w_ * xlvS[s].x);                                         \
    acc.y = fmaf(acc.y, sc_, w_ * xlvS[s].y);                                         \
    acc.z = fmaf(acc.z, sc_, w_ * xlvS[s].z);                                         \
    acc.w = fmaf(acc.w, sc_, w_ * xlvS[s].w);                                         \
} while (0)

template <int H, int RELU>
__global__ __launch_bounds__(256, 4) void k_gat(
    const float* __restrict__ xl, const float* __restrict__ xr,
    const float* __restrict__ ea, const float* __restrict__ loop_attr,
    const int2* __restrict__ elist2, const int* __restrict__ rowptr,
    const float* __restrict__ We, const float* __restrict__ att,
    const float* __restrict__ bias, float* __restrict__ out)
{
    int t = threadIdx.x;
    int lane = t & 63;
    int n = __builtin_amdgcn_readfirstlane(blockIdx.x * 4 + (t >> 6));
    int base = lane * 4;

    float4 weR[ED_DIM];
    #pragma unroll
    for (int d = 0; d < ED_DIM; ++d)
        weR[d] = *(const float4*)(We + d * FEAT + base);

    float4 attR = *(const float4*)(att + base);
    float4 xrv  = *(const float4*)(xr + (size_t)n * FEAT + base);

    float m = -INFINITY, z = 0.f;
    float4 acc = {0.f, 0.f, 0.f, 0.f};

    int p0 = rowptr[n], p1 = rowptr[n + 1];   // p1 > p0 guaranteed (self-loop)
    int pe = p1 - 1;

    int2   eS[2];
    float4 evS[2][4];
    float4 xlvS[2];

    eS[0] = elist2[p0];
    { int pc = p0 + 1 > pe ? pe : p0 + 1; eS[1] = elist2[pc]; }
    XELOAD(0);

    int p = p0;
    while (true) {
        XELOAD(1);
        { int pn = p + 2 > pe ? pe : p + 2; eS[0] = elist2[pn]; }
        COMPUTE(0);
        if (++p >= p1) break;
        XELOAD(0);
        { int pn = p + 2 > pe ? pe : p + 2; eS[1] = elist2[pn]; }
        COMPUTE(1);
        if (++p >= p1) break;
    }

    float inv = 1.0f / (z + 1e-16f);
    float4 bs = *(const float4*)(bias + base);
    float4 o;
    o.x = fmaf(acc.x, inv, bs.x);
    o.y = fmaf(acc.y, inv, bs.y);
    o.z = fmaf(acc.z, inv, bs.z);
    o.w = fmaf(acc.w, inv, bs.w);
    if (RELU) {
        o.x = fmaxf(o.x, 0.f); o.y = fmaxf(o.y, 0.f);
        o.z = fmaxf(o.z, 0.f); o.w = fmaxf(o.w, 0.f);
    }
    *(float4*)(out + (size_t)n * FEAT + base) = o;
}

// ---------------- gate score: gate[n] = ghid[n,:] @ W2 + b2 ----------------
__global__ __launch_bounds__(256) void k_gate_score(const float* __restrict__ ghid,
    const float* __restrict__ W2, const float* __restrict__ b2, float* __restrict__ gate)
{
    int lane = threadIdx.x & 63;
    int n = blockIdx.x * 4 + (threadIdx.x >> 6);
    float v = ghid[(size_t)n * 128 + lane] * W2[lane] + ghid[(size_t)n * 128 + lane + 64] * W2[lane + 64];
    #pragma unroll
    for (int off = 32; off > 0; off >>= 1) v += __shfl_xor(v, off, 64);
    if (lane == 0) gate[n] = v + b2[0];
}

// ---------------- attentional pooling: one block per batch segment ----------------
__device__ __forceinline__ int lbound(const int* a, int n, int v)
{
    int lo = 0, hi = n;
    while (lo < hi) { int mid = (lo + hi) >> 1; if (a[mid] < v) lo = mid + 1; else hi = mid; }
    return lo;
}

__global__ __launch_bounds__(256) void k_pool(const float* __restrict__ gate,
    const float* __restrict__ h, const int* __restrict__ batch, float* __restrict__ g)
{
    int b = blockIdx.x;
    int t = threadIdx.x;
    __shared__ float red[256];
    int start = lbound(batch, N_NODES, b);
    int end   = lbound(batch, N_NODES, b + 1);

    float mx = -INFINITY;
    for (int n = start + t; n < end; n += 256) mx = fmaxf(mx, gate[n]);
    red[t] = mx; __syncthreads();
    for (int s = 128; s; s >>= 1) { if (t < s) red[t] = fmaxf(red[t], red[t + s]); __syncthreads(); }
    float m = red[0];
    __syncthreads();

    float zs = 0.f;
    for (int n = start + t; n < end; n += 256) zs += __expf(gate[n] - m);
    red[t] = zs; __syncthreads();
    for (int s = 128; s; s >>= 1) { if (t < s) red[t] += red[t + s]; __syncthreads(); }
    float z = red[0];

    float gs = 0.f;
    for (int n = start; n < end; ++n) gs += __expf(gate[n] - m) * h[(size_t)n * FEAT + t];
    g[b * FEAT + t] = gs / (z + 1e-16f);
}

// ---------------- regression head: per-batch tiny MLP ----------------
__global__ __launch_bounds__(128) void k_reg(const float* __restrict__ g,
    const float* __restrict__ W1, const float* __restrict__ b1,
    const float* __restrict__ W2, const float* __restrict__ b2, float* __restrict__ out)
{
    int b = blockIdx.x, t = threadIdx.x;
    __shared__ float sg[FEAT];
    sg[t] = g[b * FEAT + t];
    sg[t + 128] = g[b * FEAT + t + 128];
    __syncthreads();
    float hv = b1[t];
    for (int k = 0; k < FEAT; ++k) hv += sg[k] * W1[k * 128 + t];
    hv = fmaxf(hv, 0.f);
    __shared__ float p0s[128], p1s[128];
    p0s[t] = hv * W2[t * 2 + 0];
    p1s[t] = hv * W2[t * 2 + 1];
    __syncthreads();
    for (int s = 64; s; s >>= 1) {
        if (t < s) { p0s[t] += p0s[t + s]; p1s[t] += p1s[t + s]; }
        __syncthreads();
    }
    if (t == 0) { out[b * 2 + 0] = p0s[0] + b2[0]; out[b * 2 + 1] = p1s[0] + b2[1]; }
}

// ---------------- launch ----------------
extern "C" void kernel_launch(void* const* d_in, const int* in_sizes, int n_in,
                              void* d_out, int out_size, void* d_ws, size_t ws_size,
                              hipStream_t stream)
{
    const float* x       = (const float*)d_in[0];
    const int*   ei      = (const int*)d_in[1];   // [2,E]
    const float* ea      = (const float*)d_in[2];
    const int*   batch   = (const int*)d_in[3];
    const float* c1_Wl   = (const float*)d_in[5];
    const float* c1_bl   = (const float*)d_in[6];
    const float* c1_Wr   = (const float*)d_in[7];
    const float* c1_br   = (const float*)d_in[8];
    const float* c1_We   = (const float*)d_in[9];
    const float* c1_att  = (const float*)d_in[10];
    const float* c1_bias = (const float*)d_in[11];
    const float* c2_Wl   = (const float*)d_in[12];
    const float* c2_bl   = (const float*)d_in[13];
    const float* c2_Wr   = (const float*)d_in[14];
    const float* c2_br   = (const float*)d_in[15];
    const float* c2_We   = (const float*)d_in[16];
    const float* c2_att  = (const float*)d_in[17];
    const float* c2_bias = (const float*)d_in[18];
    const float* c3_Wl   = (const float*)d_in[19];
    const float* c3_bl   = (const float*)d_in[20];
    const float* c3_Wr   = (const float*)d_in[21];
    const float* c3_br   = (const float*)d_in[22];
    const float* c3_We   = (const float*)d_in[23];
    const float* c3_att  = (const float*)d_in[24];
    const float* c3_bias = (const float*)d_in[25];
    const float* gate_W1 = (const float*)d_in[26];
    const float* gate_b1 = (const float*)d_in[27];
    const float* gate_W2 = (const float*)d_in[28];
    const float* gate_b2 = (const float*)d_in[29];
    const float* reg_W1  = (const float*)d_in[30];
    const float* reg_b1  = (const float*)d_in[31];
    const float* reg_W2  = (const float*)d_in[32];
    const float* reg_b2  = (const float*)d_in[33];

    const int* srcArr = ei;            // row 0
    const int* dstArr = ei + N_EDGES;  // row 1

    float* ws = (float*)d_ws;
    size_t off = 0;
    auto alloc = [&](size_t nf) { float* p = ws + off; off += (nf + 63) & ~(size_t)63; return p; };
    float* xl        = alloc((size_t)N_NODES * FEAT);
    float* xr        = alloc((size_t)N_NODES * FEAT);
    float* h         = alloc((size_t)N_NODES * FEAT);
    float* loop_attr = alloc((size_t)N_NODES * ED_DIM);
    float* gpool     = alloc((size_t)BATCH * FEAT);
    unsigned short* Ah = (unsigned short*)alloc((size_t)N_NODES * FEAT / 2);  // bf16 hi
    unsigned short* Al = (unsigned short*)alloc((size_t)N_NODES * FEAT / 2);  // bf16 lo
    unsigned short* wlT_h = (unsigned short*)alloc(FEAT * FEAT / 2);
    unsigned short* wlT_l = (unsigned short*)alloc(FEAT * FEAT / 2);
    unsigned short* wrT_h = (unsigned short*)alloc(FEAT * FEAT / 2);
    unsigned short* wrT_l = (unsigned short*)alloc(FEAT * FEAT / 2);
    int* ibase  = (int*)(ws + off);
    int* deg    = ibase;
    int* fill   = ibase + N_NODES;
    int* rowptr = ibase + 2 * N_NODES;            // N+1 ints
    int* bsum   = ibase + 3 * N_NODES + 64;
    int* boff   = bsum + 256;
    int2* elist2 = (int2*)(boff + 256);           // ETOT int2

    // aliases at disjoint lifetimes
    float* ghid = xl;                       // after L3 gat, xl is dead
    float* gate = xr;

    hipMemsetAsync(deg, 0, (size_t)2 * N_NODES * sizeof(int), stream);

    // CSR build, then self-loop mean attrs from CSR
    k_deg<<<(ETOT + 255) / 256, 256, 0, stream>>>(dstArr, deg);
    k_scan1<<<NCHUNK, 256, 0, stream>>>(deg, bsum);
    k_scan2<<<1, 256, 0, stream>>>(bsum, boff, rowptr);
    k_scan3<<<NCHUNK, 256, 0, stream>>>(deg, boff, rowptr);
    k_fill<<<(ETOT + 255) / 256, 256, 0, stream>>>(srcArr, dstArr, rowptr, fill, elist2);
    k_loop_csr<<<(N_NODES * ED_DIM + 255) / 256, 256, 0, stream>>>(elist2, rowptr, ea, loop_attr);

    // layer 1 (in: x [N,128], K=128)
    {
        int n4 = N_NODES * IN_DIM / 4;
        k_cvt<<<(n4 + 255) / 256, 256, 0, stream>>>(x, Ah, Al, n4);
        k_cvtT<<<(IN_DIM * FEAT + 255) / 256, 256, 0, stream>>>(c1_Wl, wlT_h, wlT_l, IN_DIM, FEAT);
        k_cvtT<<<(IN_DIM * FEAT + 255) / 256, 256, 0, stream>>>(c1_Wr, wrT_h, wrT_l, IN_DIM, FEAT);
        launch_mgemm(Ah, Al, wlT_h, wlT_l, c1_bl, xl, N_NODES, FEAT, IN_DIM, 0, stream);
        launch_mgemm(Ah, Al, wrT_h, wrT_l, c1_br, xr, N_NODES, FEAT, IN_DIM, 0, stream);
    }
    k_gat<4, 1><<<N_NODES / 4, 256, 0, stream>>>(xl, xr, ea, loop_attr, elist2, rowptr,
                                                 c1_We, c1_att, c1_bias, h);
    // layer 2 (K=256)
    {
        int n4 = N_NODES * FEAT / 4;
        k_cvt<<<(n4 + 255) / 256, 256, 0, stream>>>(h, Ah, Al, n4);
        k_cvtT<<<(FEAT * FEAT + 255) / 256, 256, 0, stream>>>(c2_Wl, wlT_h, wlT_l, FEAT, FEAT);
        k_cvtT<<<(FEAT * FEAT + 255) / 256, 256, 0, stream>>>(c2_Wr, wrT_h, wrT_l, FEAT, FEAT);
        launch_mgemm(Ah, Al, wlT_h, wlT_l, c2_bl, xl, N_NODES, FEAT, FEAT, 0, stream);
        launch_mgemm(Ah, Al, wrT_h, wrT_l, c2_br, xr, N_NODES, FEAT, FEAT, 0, stream);
    }
    k_gat<4, 1><<<N_NODES / 4, 256, 0, stream>>>(xl, xr, ea, loop_attr, elist2, rowptr,
                                                 c2_We, c2_att, c2_bias, h);
    // layer 3 (heads=1, no relu)
    {
        int n4 = N_NODES * FEAT / 4;
        k_cvt<<<(n4 + 255) / 256, 256, 0, stream>>>(h, Ah, Al, n4);
        k_cvtT<<<(FEAT * FEAT + 255) / 256, 256, 0, stream>>>(c3_Wl, wlT_h, wlT_l, FEAT, FEAT);
        k_cvtT<<<(FEAT * FEAT + 255) / 256, 256, 0, stream>>>(c3_Wr, wrT_h, wrT_l, FEAT, FEAT);
        launch_mgemm(Ah, Al, wlT_h, wlT_l, c3_bl, xl, N_NODES, FEAT, FEAT, 0, stream);
        launch_mgemm(Ah, Al, wrT_h, wrT_l, c3_br, xr, N_NODES, FEAT, FEAT, 0, stream);
    }
    k_gat<1, 0><<<N_NODES / 4, 256, 0, stream>>>(xl, xr, ea, loop_attr, elist2, rowptr,
                                                 c3_We, c3_att, c3_bias, h);

    // pooling + head (gate hidden GEMM: K=256, N=128, relu)
    {
        int n4 = N_NODES * FEAT / 4;
        k_cvt<<<(n4 + 255) / 256, 256, 0, stream>>>(h, Ah, Al, n4);
        k_cvtT<<<(FEAT * 128 + 255) / 256, 256, 0, stream>>>(gate_W1, wlT_h, wlT_l, FEAT, 128);
        launch_mgemm(Ah, Al, wlT_h, wlT_l, gate_b1, ghid, N_NODES, 128, FEAT, 1, stream);
    }
    k_gate_score<<<N_NODES / 4, 256, 0, stream>>>(ghid, gate_W2, gate_b2, gate);
    k_pool<<<BATCH, 256, 0, stream>>>(gate, h, batch, gpool);
    k_reg<<<BATCH, 128, 0, stream>>>(gpool, reg_W1, reg_b1, reg_W2, reg_b2, (float*)d_out);
}